// Round 1
// baseline (2664.479 us; speedup 1.0000x reference)
//
#include <hip/hip_runtime.h>
#include <hip/hip_bf16.h>

// Shapes (fixed by the problem)
#define BB 2
#define SS 1024
#define DD 1024
#define HH 16
#define DKV 64
#define EE 8
#define FF 2048
#define FSH2 4096

// ---------------------------------------------------------------- LayerNorm
__global__ __launch_bounds__(256) void ln_kernel(const float* __restrict__ x,
                                                 const float* __restrict__ w,
                                                 float* __restrict__ y) {
    __shared__ float red[4], red2[4];
    const int row = blockIdx.x;
    const int t = threadIdx.x;
    const float4* xr = (const float4*)(x + (size_t)row * DD);
    float4 v = xr[t];
    float s = v.x + v.y + v.z + v.w;
    float q = v.x * v.x + v.y * v.y + v.z * v.z + v.w * v.w;
    for (int o = 32; o; o >>= 1) { s += __shfl_down(s, o); q += __shfl_down(q, o); }
    if ((t & 63) == 0) { red[t >> 6] = s; red2[t >> 6] = q; }
    __syncthreads();
    float S = red[0] + red[1] + red[2] + red[3];
    float Q = red2[0] + red2[1] + red2[2] + red2[3];
    float mu = S * (1.0f / DD);
    float var = Q * (1.0f / DD) - mu * mu;
    float inv = rsqrtf(var + 1e-8f);
    const float4* wr = (const float4*)w;
    float4 wv = wr[t];
    float4 o4;
    o4.x = (v.x - mu) * inv * wv.x;
    o4.y = (v.y - mu) * inv * wv.y;
    o4.z = (v.z - mu) * inv * wv.z;
    o4.w = (v.w - mu) * inv * wv.w;
    ((float4*)(y + (size_t)row * DD))[t] = o4;
}

// ------------------------------------------- Generic f32 GEMM: C = A@W + bias (+addsrc)
// A: MxK row-major, W: KxN row-major. 64x64 tile, TK=16, 256 threads, 4x4/thread.
__global__ __launch_bounds__(256) void gemm_bias(const float* __restrict__ A,
                                                 const float* __restrict__ W,
                                                 const float* __restrict__ bias,
                                                 const float* __restrict__ addsrc,
                                                 float* __restrict__ C,
                                                 int M, int N, int K) {
    __shared__ __align__(16) float As[16][68];
    __shared__ __align__(16) float Ws[16][68];
    const int t = threadIdx.x;
    const int tm = t >> 4, tn = t & 15;
    const int m0 = blockIdx.y * 64, n0 = blockIdx.x * 64;
    float acc[4][4] = {};
    for (int k0 = 0; k0 < K; k0 += 16) {
#pragma unroll
        for (int r = 0; r < 4; ++r) {
            int idx = t + 256 * r;
            int mm = idx >> 4, kk = idx & 15;
            As[kk][mm] = A[(size_t)(m0 + mm) * K + k0 + kk];
            int nn = idx & 63, kw = idx >> 6;
            Ws[kw][nn] = W[(size_t)(k0 + kw) * N + n0 + nn];
        }
        __syncthreads();
#pragma unroll
        for (int kk = 0; kk < 16; ++kk) {
            float a[4], w[4];
#pragma unroll
            for (int i = 0; i < 4; ++i) a[i] = As[kk][tm * 4 + i];
#pragma unroll
            for (int j = 0; j < 4; ++j) w[j] = Ws[kk][tn * 4 + j];
#pragma unroll
            for (int i = 0; i < 4; ++i)
#pragma unroll
                for (int j = 0; j < 4; ++j) acc[i][j] += a[i] * w[j];
        }
        __syncthreads();
    }
#pragma unroll
    for (int i = 0; i < 4; ++i) {
        int m = m0 + tm * 4 + i;
#pragma unroll
        for (int j = 0; j < 4; ++j) {
            int n = n0 + tn * 4 + j;
            float v = acc[i][j] + bias[n];
            if (addsrc) v += addsrc[(size_t)m * N + n];
            C[(size_t)m * N + n] = v;
        }
    }
}

// --------------------- silu-gated double GEMM: out = silu(A@W1+b1) * (A@W3+b3)
// Dense mode (tok_list==nullptr): rows are 0..M-1, blockIdx.z must be 0.
// Grouped mode: expert e = blockIdx.z, rows gathered via tok_list, out rows at offs[e]+i.
__global__ __launch_bounds__(256) void gemm_silu2(const float* __restrict__ A,
                                                  const float* __restrict__ W1,
                                                  const float* __restrict__ B1,
                                                  const float* __restrict__ W3,
                                                  const float* __restrict__ B3,
                                                  float* __restrict__ Out,
                                                  int M, int N, int K,
                                                  const int* __restrict__ tok_list,
                                                  const int* __restrict__ cnt,
                                                  const int* __restrict__ offs) {
    __shared__ __align__(16) float As[16][68];
    __shared__ __align__(16) float W1s[16][68];
    __shared__ __align__(16) float W3s[16][68];
    __shared__ int rows[64];
    const int e = blockIdx.z;
    int ne = M, base = 0;
    const float *w1 = W1, *w3 = W3, *b1 = B1, *b3 = B3;
    if (tok_list) {
        ne = cnt[e];
        base = offs[e];
        if ((int)blockIdx.y * 64 >= ne) return;
        w1 = W1 + (size_t)e * K * N;
        w3 = W3 + (size_t)e * K * N;
        b1 = B1 + (size_t)e * N;
        b3 = B3 + (size_t)e * N;
    }
    const int t = threadIdx.x;
    const int m0 = blockIdx.y * 64, n0 = blockIdx.x * 64;
    if (t < 64) {
        int i = m0 + t;
        int r;
        if (tok_list) { int ic = (i < ne) ? i : (ne - 1); r = tok_list[e * 2048 + ic]; }
        else r = i;
        rows[t] = r;
    }
    __syncthreads();
    const int tm = t >> 4, tn = t & 15;
    float acc1[4][4] = {}, acc3[4][4] = {};
    for (int k0 = 0; k0 < K; k0 += 16) {
#pragma unroll
        for (int r = 0; r < 4; ++r) {
            int idx = t + 256 * r;
            int mm = idx >> 4, kk = idx & 15;
            As[kk][mm] = A[(size_t)rows[mm] * K + k0 + kk];
            int nn = idx & 63, kw = idx >> 6;
            W1s[kw][nn] = w1[(size_t)(k0 + kw) * N + n0 + nn];
            W3s[kw][nn] = w3[(size_t)(k0 + kw) * N + n0 + nn];
        }
        __syncthreads();
#pragma unroll
        for (int kk = 0; kk < 16; ++kk) {
            float a[4], u[4], g[4];
#pragma unroll
            for (int i = 0; i < 4; ++i) a[i] = As[kk][tm * 4 + i];
#pragma unroll
            for (int j = 0; j < 4; ++j) { u[j] = W1s[kk][tn * 4 + j]; g[j] = W3s[kk][tn * 4 + j]; }
#pragma unroll
            for (int i = 0; i < 4; ++i)
#pragma unroll
                for (int j = 0; j < 4; ++j) {
                    acc1[i][j] += a[i] * u[j];
                    acc3[i][j] += a[i] * g[j];
                }
        }
        __syncthreads();
    }
#pragma unroll
    for (int i = 0; i < 4; ++i) {
        int li = m0 + tm * 4 + i;
        if (li >= ne) continue;
#pragma unroll
        for (int j = 0; j < 4; ++j) {
            int n = n0 + tn * 4 + j;
            float av = acc1[i][j] + b1[n];
            float gv = acc3[i][j] + b3[n];
            float sil = av / (1.0f + __expf(-av));
            Out[(size_t)(base + li) * N + n] = sil * gv;
        }
    }
}

// ------------------ MoE second GEMM + weighted scatter to y0/y1 (no atomics)
__global__ __launch_bounds__(256) void moe_out_kernel(const float* __restrict__ mid,
                                                      const float* __restrict__ W2,
                                                      const float* __restrict__ B2,
                                                      const int* __restrict__ tok_list,
                                                      const int* __restrict__ cnt,
                                                      const int* __restrict__ offs,
                                                      const float* __restrict__ comb,
                                                      const int* __restrict__ idx0,
                                                      float* __restrict__ y0,
                                                      float* __restrict__ y1) {
    const int N = DD, K = FF;
    __shared__ __align__(16) float As[16][68];
    __shared__ __align__(16) float Ws[16][68];
    const int e = blockIdx.z;
    const int ne = cnt[e];
    if ((int)blockIdx.y * 64 >= ne) return;
    const int base = offs[e];
    const float* w2 = W2 + (size_t)e * K * N;
    const float* b2 = B2 + (size_t)e * N;
    const int t = threadIdx.x;
    const int tm = t >> 4, tn = t & 15;
    const int m0 = blockIdx.y * 64, n0 = blockIdx.x * 64;
    float acc[4][4] = {};
    for (int k0 = 0; k0 < K; k0 += 16) {
#pragma unroll
        for (int r = 0; r < 4; ++r) {
            int idx = t + 256 * r;
            int mm = idx >> 4, kk = idx & 15;
            int mi = m0 + mm; if (mi >= ne) mi = ne - 1;
            As[kk][mm] = mid[(size_t)(base + mi) * K + k0 + kk];
            int nn = idx & 63, kw = idx >> 6;
            Ws[kw][nn] = w2[(size_t)(k0 + kw) * N + n0 + nn];
        }
        __syncthreads();
#pragma unroll
        for (int kk = 0; kk < 16; ++kk) {
            float a[4], w[4];
#pragma unroll
            for (int i = 0; i < 4; ++i) a[i] = As[kk][tm * 4 + i];
#pragma unroll
            for (int j = 0; j < 4; ++j) w[j] = Ws[kk][tn * 4 + j];
#pragma unroll
            for (int i = 0; i < 4; ++i)
#pragma unroll
                for (int j = 0; j < 4; ++j) acc[i][j] += a[i] * w[j];
        }
        __syncthreads();
    }
#pragma unroll
    for (int i = 0; i < 4; ++i) {
        int li = m0 + tm * 4 + i;
        if (li >= ne) continue;
        int tok = tok_list[e * 2048 + li];
        float wgt = comb[tok * 8 + e];
        float* dst = (idx0[tok] == e) ? y0 : y1;
#pragma unroll
        for (int j = 0; j < 4; ++j) {
            int n = n0 + tn * 4 + j;
            dst[(size_t)tok * DD + n] = wgt * (acc[i][j] + b2[n]);
        }
    }
}

// ---------------------------------------------------------------- Attention
// One block per (b, h, q). Two-pass softmax, K staged in LDS tiles of 64.
__global__ __launch_bounds__(256) void attn_kernel(const float* __restrict__ Q,
                                                   const float* __restrict__ Kk,
                                                   const float* __restrict__ V,
                                                   const float* __restrict__ pe,
                                                   const float* __restrict__ mask,
                                                   const int* __restrict__ sp_ptr,
                                                   float* __restrict__ O) {
    __shared__ float sq[64];
    __shared__ __align__(16) float kt[64][68];
    __shared__ float scores[SS];
    __shared__ float red[4];
    __shared__ float opart[4][64];
    const int bid = blockIdx.x;  // b*H*S + h*S + qs
    const int qs = bid & (SS - 1);
    const int h = (bid >> 10) & (HH - 1);
    const int b = bid >> 14;
    const int sp = sp_ptr[0];
    const int t = threadIdx.x;
    const size_t qoff = ((size_t)(b * SS + qs)) * DD + h * DKV;
    if (t < 64) sq[t] = Q[qoff + t];
    __syncthreads();
    const size_t kbase = (size_t)b * SS * DD + h * DKV;
    const size_t pbase = (size_t)h * SS * SS + (size_t)(sp + qs) * SS + sp;
    for (int kt0 = 0; kt0 < SS; kt0 += 64) {
        __syncthreads();
#pragma unroll
        for (int r = 0; r < 16; ++r) {
            int idx = t + 256 * r;
            int key = idx >> 6, d = idx & 63;
            kt[key][d] = Kk[kbase + (size_t)(kt0 + key) * DD + d];
        }
        __syncthreads();
        const int key = t >> 2, part = t & 3;
        const float* kr = &kt[key][part * 16];
        const float* qr = &sq[part * 16];
        float p = 0.f;
#pragma unroll
        for (int j = 0; j < 16; ++j) p += qr[j] * kr[j];
        p += __shfl_down(p, 2, 4);
        p += __shfl_down(p, 1, 4);
        if (part == 0) {
            int kg = kt0 + key;
            scores[kg] = p * 0.125f + pe[pbase + kg] + mask[(size_t)qs * SS + kg];
        }
    }
    __syncthreads();
    // softmax over scores[0..1023]
    float m = -3.4e38f;
#pragma unroll
    for (int r = 0; r < 4; ++r) m = fmaxf(m, scores[t + 256 * r]);
    for (int o = 32; o; o >>= 1) m = fmaxf(m, __shfl_down(m, o));
    if ((t & 63) == 0) red[t >> 6] = m;
    __syncthreads();
    m = fmaxf(fmaxf(red[0], red[1]), fmaxf(red[2], red[3]));
    __syncthreads();
    float s = 0.f;
#pragma unroll
    for (int r = 0; r < 4; ++r) {
        float ev = __expf(scores[t + 256 * r] - m);
        scores[t + 256 * r] = ev;
        s += ev;
    }
    for (int o = 32; o; o >>= 1) s += __shfl_down(s, o);
    if ((t & 63) == 0) red[t >> 6] = s;
    __syncthreads();
    s = red[0] + red[1] + red[2] + red[3];
    const float inv = 1.0f / s;
    // PV
    const int dv = t & 63, seg = t >> 6;
    const size_t vbase = (size_t)b * SS * DD + h * DKV + dv;
    float acc = 0.f;
    for (int key = seg * 256; key < seg * 256 + 256; ++key)
        acc += scores[key] * V[vbase + (size_t)key * DD];
    opart[seg][dv] = acc;
    __syncthreads();
    if (t < 64) {
        float ov = (opart[0][t] + opart[1][t] + opart[2][t] + opart[3][t]) * inv;
        O[qoff + t] = ov;
    }
}

// ---------------------------------------------------------------- Gating
__global__ __launch_bounds__(64) void gate_kernel(const float* __restrict__ hn,
                                                  const float* __restrict__ gw,
                                                  const float* __restrict__ gb,
                                                  float* __restrict__ comb,
                                                  int* __restrict__ idx0,
                                                  int* __restrict__ cnt,
                                                  int* __restrict__ tok_list) {
    __shared__ float lg[8];
    const int tok = blockIdx.x;
    const int lane = threadIdx.x;
    const int e = lane >> 3, chunk = lane & 7;
    const float* hr = hn + (size_t)tok * DD + chunk * 128;
    const float* gr = gw + (size_t)e * DD + chunk * 128;
    float p = 0.f;
    for (int j = 0; j < 128; ++j) p += hr[j] * gr[j];
    p += __shfl_down(p, 4, 8);
    p += __shfl_down(p, 2, 8);
    p += __shfl_down(p, 1, 8);
    if (chunk == 0) lg[e] = p + gb[e];
    __syncthreads();
    if (lane == 0) {
        float mx = lg[0];
        for (int i = 1; i < 8; ++i) mx = fmaxf(mx, lg[i]);
        float pr[8]; float ssum = 0.f;
        for (int i = 0; i < 8; ++i) { pr[i] = __expf(lg[i] - mx); ssum += pr[i]; }
        float is = 1.0f / ssum;
        for (int i = 0; i < 8; ++i) pr[i] *= is;
        int i1 = 0;
        for (int i = 1; i < 8; ++i) if (pr[i] > pr[i1]) i1 = i;
        int i2 = -1;
        for (int i = 0; i < 8; ++i) { if (i == i1) continue; if (i2 < 0 || pr[i] > pr[i2]) i2 = i; }
        float w0 = pr[i1], w1 = pr[i2];
        float nrm = 1.0f / (w0 + w1 + 1e-20f);
        w0 *= nrm; w1 *= nrm;
        for (int i = 0; i < 8; ++i) comb[tok * 8 + i] = 0.0f;
        comb[tok * 8 + i1] = w0;
        comb[tok * 8 + i2] = w1;
        idx0[tok] = i1;
        int s1 = atomicAdd(&cnt[i1], 1); tok_list[i1 * 2048 + s1] = tok;
        int s2 = atomicAdd(&cnt[i2], 1); tok_list[i2 * 2048 + s2] = tok;
    }
}

__global__ void init_cnt(int* cnt) { if (threadIdx.x < 8) cnt[threadIdx.x] = 0; }

__global__ void prefix_kernel(const int* __restrict__ cnt, int* __restrict__ offs) {
    if (threadIdx.x == 0) {
        int a = 0;
        for (int e = 0; e < 8; ++e) { offs[e] = a; a += cnt[e]; }
    }
}

// ---------------------------------------------------------------- Final sum
__global__ __launch_bounds__(256) void final_kernel(const float* __restrict__ x2,
                                                    const float* __restrict__ y0,
                                                    const float* __restrict__ y1,
                                                    const float* __restrict__ sh,
                                                    float* __restrict__ out) {
    size_t i = (size_t)blockIdx.x * 256 + threadIdx.x;
    float4 a = ((const float4*)x2)[i];
    float4 b = ((const float4*)y0)[i];
    float4 c = ((const float4*)y1)[i];
    float4 d = ((const float4*)sh)[i];
    float4 o;
    o.x = a.x + b.x + c.x + d.x;
    o.y = a.y + b.y + c.y + d.y;
    o.z = a.z + b.z + c.z + d.z;
    o.w = a.w + b.w + c.w + d.w;
    ((float4*)out)[i] = o;
}

extern "C" void kernel_launch(void* const* d_in, const int* in_sizes, int n_in,
                              void* d_out, int out_size, void* d_ws, size_t ws_size,
                              hipStream_t stream) {
    const float* x   = (const float*)d_in[0];
    const int*   sp  = (const int*)d_in[1];
    const float* mask= (const float*)d_in[2];
    const float* pe  = (const float*)d_in[3];
    const float* anw = (const float*)d_in[4];
    const float* fnw = (const float*)d_in[5];
    const float* wq  = (const float*)d_in[6];  const float* bq  = (const float*)d_in[7];
    const float* wk  = (const float*)d_in[8];  const float* bk  = (const float*)d_in[9];
    const float* wv  = (const float*)d_in[10]; const float* bv  = (const float*)d_in[11];
    const float* wo  = (const float*)d_in[12]; const float* bo  = (const float*)d_in[13];
    const float* gw  = (const float*)d_in[14]; const float* gb  = (const float*)d_in[15];
    const float* ew1 = (const float*)d_in[16]; const float* eb1 = (const float*)d_in[17];
    const float* ew2 = (const float*)d_in[18]; const float* eb2 = (const float*)d_in[19];
    const float* ew3 = (const float*)d_in[20]; const float* eb3 = (const float*)d_in[21];
    const float* sw1 = (const float*)d_in[22]; const float* sb1 = (const float*)d_in[23];
    const float* sw2 = (const float*)d_in[24]; const float* sb2 = (const float*)d_in[25];
    const float* sw3 = (const float*)d_in[26]; const float* sb3 = (const float*)d_in[27];

    float* ws = (float*)d_ws;
    const size_t M2 = (size_t)2048 * 1024;  // 2M floats per slot
    // slot reuse plan:
    // s0: xn -> o -> y0 | s1: q -> hn | s2: k -> y1 | s3: v -> shared | s4: x2
    // s5..s8: mid (8M floats) | then small buffers
    float* xn   = ws;
    float* q    = ws + 1 * M2;
    float* kbuf = ws + 2 * M2;
    float* vbuf = ws + 3 * M2;
    float* x2   = ws + 4 * M2;
    float* mid  = ws + 5 * M2;            // 8M floats (covers 4096x2048 and 2048x4096)
    float* small= ws + 9 * M2;
    float* comb = small;                  // 2048*8
    int* idx0   = (int*)(small + 16384);  // 2048
    int* cnt    = idx0 + 2048;            // 8
    int* offs   = cnt + 8;                // 8
    int* tok_list = offs + 8;             // 8*2048
    float* o   = xn;    // reuse after xn dead
    float* hn  = q;     // reuse after q dead
    float* y0  = xn;
    float* y1  = kbuf;
    float* sh  = vbuf;

    // 1. attn layernorm
    ln_kernel<<<2048, 256, 0, stream>>>(x, anw, xn);
    // 2. QKV projections
    dim3 g_nk(16, 32);
    gemm_bias<<<g_nk, 256, 0, stream>>>(xn, wq, bq, nullptr, q,    2048, 1024, 1024);
    gemm_bias<<<g_nk, 256, 0, stream>>>(xn, wk, bk, nullptr, kbuf, 2048, 1024, 1024);
    gemm_bias<<<g_nk, 256, 0, stream>>>(xn, wv, bv, nullptr, vbuf, 2048, 1024, 1024);
    // 3. attention (writes o == xn slot; xn no longer needed)
    attn_kernel<<<BB * HH * SS, 256, 0, stream>>>(q, kbuf, vbuf, pe, mask, sp, o);
    // 4. output projection + residual
    gemm_bias<<<g_nk, 256, 0, stream>>>(o, wo, bo, x, x2, 2048, 1024, 1024);
    // 5. ffn layernorm
    ln_kernel<<<2048, 256, 0, stream>>>(x2, fnw, hn);
    // 6. gating + token bucketing
    init_cnt<<<1, 64, 0, stream>>>(cnt);
    gate_kernel<<<2048, 64, 0, stream>>>(hn, gw, gb, comb, idx0, cnt, tok_list);
    prefix_kernel<<<1, 64, 0, stream>>>(cnt, offs);
    // 7. routed experts: mid = silu(hn@ew1+b1)*(hn@ew3+b3) (grouped, gathered rows)
    gemm_silu2<<<dim3(FF / 64, 32, EE), 256, 0, stream>>>(hn, ew1, eb1, ew3, eb3, mid,
                                                          2048, FF, 1024, tok_list, cnt, offs);
    // 8. routed experts: y = comb * (mid@ew2+b2), scattered to y0/y1 by rank
    moe_out_kernel<<<dim3(DD / 64, 32, EE), 256, 0, stream>>>(mid, ew2, eb2, tok_list, cnt, offs,
                                                              comb, idx0, y0, y1);
    // 9. shared expert mid (dense), reuses mid buffer
    gemm_silu2<<<dim3(FSH2 / 64, 32, 1), 256, 0, stream>>>(hn, sw1, sb1, sw3, sb3, mid,
                                                           2048, FSH2, 1024, nullptr, nullptr, nullptr);
    // 10. shared expert out
    gemm_bias<<<g_nk, 256, 0, stream>>>(mid, sw2, sb2, nullptr, sh, 2048, 1024, FSH2);
    // 11. out = x2 + y0 + y1 + shared
    final_kernel<<<2048, 256, 0, stream>>>(x2, y0, y1, sh, (float*)d_out);
}

// Round 2
// 1605.991 us; speedup vs baseline: 1.6591x; 1.6591x over previous
//
#include <hip/hip_runtime.h>
#include <hip/hip_bf16.h>

// Shapes (fixed by the problem)
#define BB 2
#define SS 1024
#define DD 1024
#define HH 16
#define DKV 64
#define EE 8
#define FF 2048
#define FSH2 4096

typedef __attribute__((ext_vector_type(8))) short bf16x8;   // 8 bf16 = 4 VGPR (MFMA A/B frag)
typedef __attribute__((ext_vector_type(4))) float f32x4;    // MFMA C/D frag

// epilogue modes
#define EPI_PLAIN 0
#define EPI_SILUMUL 1
#define EPI_SCATTER 2
// A-row modes
#define AM_DENSE 0
#define AM_GATHER 1
#define AM_GROUP 2

__device__ inline unsigned pack_bf2(float lo, float hi) {
    __hip_bfloat162 h = __float22bfloat162_rn(float2{lo, hi});
    union { __hip_bfloat162 h2; unsigned u; } c; c.h2 = h; return c.u;
}

// ------------------------------------------------------------------
// bf16-MFMA GEMM, 128x128 tile, BK=32, 256 threads (4 waves as 2x2),
// each wave owns a 64x64 quadrant = 4x4 frags of 16x16.
// A (MxK f32) and W (KxN f32) are converted to bf16 during LDS staging.
// As: row-major [128][40] bf16 (pad-40 => 2-way bank = free).
// Bs: [col][32] bf16 with 16B-slot XOR swizzle (slot ^= col&3) => 4-way.
// ------------------------------------------------------------------
template<int EPI, int AMODE>
__global__ __launch_bounds__(256, 2) void mgemm(
    const float* __restrict__ A, const float* __restrict__ W,
    const float* __restrict__ bias, const float* __restrict__ addsrc,
    float* __restrict__ C, int M, int N, int K,
    const int* __restrict__ tok_list, const int* __restrict__ cnt,
    const int* __restrict__ offs, const float* __restrict__ comb,
    const int* __restrict__ idx0, float* __restrict__ y1)
{
    __shared__ __align__(16) unsigned short As[128 * 40];
    __shared__ __align__(16) unsigned short Bs[128 * 32];
    __shared__ int rows_s[128];
    const int t = threadIdx.x;
    const int e = (AMODE != AM_DENSE) ? blockIdx.z : 0;
    int ne = M, base = 0;
    if (AMODE != AM_DENSE) {
        ne = cnt[e];
        base = offs[e];
        if ((int)blockIdx.y * 128 >= ne) return;   // uniform exit, before any barrier
        W += (size_t)e * K * N;
        bias += (size_t)e * N;
    }
    const int m0 = blockIdx.y * 128;
    const int n0 = blockIdx.x * 128;
    if (AMODE == AM_GATHER) {
        if (t < 128) {
            int li = m0 + t; if (li >= ne) li = ne - 1;
            rows_s[t] = tok_list[e * 2048 + li];
        }
        __syncthreads();
    }
    // staging coords: A: thread t -> row t>>1, k-half (t&1)*16 (16 f32, 4x float4)
    //                 B: thread t -> col t&127, k-pair base (t>>7)*8 (16 f32, stride-N)
    const int ar = t >> 1;
    const int ac = (t & 1) * 16;
    const int bn = t & 127;
    const int bkp = (t >> 7) * 8;
    long arow;
    if (AMODE == AM_DENSE) arow = m0 + ar;
    else if (AMODE == AM_GATHER) arow = rows_s[ar];
    else { int li = m0 + ar; if (li >= ne) li = ne - 1; arow = base + li; }
    const float* Ap = A + (size_t)arow * K + ac;
    const float* Wcol = W + n0 + bn;
    // wave/frag coords
    const int l = t & 63, w = t >> 6;
    const int wr = w >> 1, wc = w & 1;
    const int lh = l >> 4, ll = l & 15;
    f32x4 acc[4][4];
#pragma unroll
    for (int i = 0; i < 4; ++i)
#pragma unroll
        for (int j = 0; j < 4; ++j) acc[i][j] = f32x4{0.f, 0.f, 0.f, 0.f};

    for (int k0 = 0; k0 < K; k0 += 32) {
        // global loads (issued before barrier -> overlap previous compute)
        const float4* ap4 = (const float4*)(Ap + k0);
        float4 a0 = ap4[0], a1 = ap4[1], a2 = ap4[2], a3 = ap4[3];
        const float* wp = Wcol + (size_t)(k0 + 2 * bkp) * N;
        float bv[16];
#pragma unroll
        for (int j = 0; j < 16; ++j) bv[j] = wp[(size_t)j * N];
        __syncthreads();   // previous tile's consumers done
        uint4 aw0, aw1;
        aw0.x = pack_bf2(a0.x, a0.y); aw0.y = pack_bf2(a0.z, a0.w);
        aw0.z = pack_bf2(a1.x, a1.y); aw0.w = pack_bf2(a1.z, a1.w);
        aw1.x = pack_bf2(a2.x, a2.y); aw1.y = pack_bf2(a2.z, a2.w);
        aw1.z = pack_bf2(a3.x, a3.y); aw1.w = pack_bf2(a3.z, a3.w);
        *(uint4*)&As[ar * 40 + ac] = aw0;
        *(uint4*)&As[ar * 40 + ac + 8] = aw1;
        uint4 bw0, bw1;
        bw0.x = pack_bf2(bv[0], bv[1]);  bw0.y = pack_bf2(bv[2], bv[3]);
        bw0.z = pack_bf2(bv[4], bv[5]);  bw0.w = pack_bf2(bv[6], bv[7]);
        bw1.x = pack_bf2(bv[8], bv[9]);  bw1.y = pack_bf2(bv[10], bv[11]);
        bw1.z = pack_bf2(bv[12], bv[13]); bw1.w = pack_bf2(bv[14], bv[15]);
        const int s0 = ((bkp >> 2) + 0) ^ (bn & 3);
        const int s1 = ((bkp >> 2) + 1) ^ (bn & 3);
        *(uint4*)&Bs[bn * 32 + s0 * 8] = bw0;
        *(uint4*)&Bs[bn * 32 + s1 * 8] = bw1;
        __syncthreads();
        bf16x8 af[4], bfr[4];
#pragma unroll
        for (int m = 0; m < 4; ++m) {
            int row = wr * 64 + m * 16 + ll;
            af[m] = *(const bf16x8*)&As[row * 40 + lh * 8];
        }
#pragma unroll
        for (int n = 0; n < 4; ++n) {
            int col = wc * 64 + n * 16 + ll;
            int slot = lh ^ (col & 3);
            bfr[n] = *(const bf16x8*)&Bs[col * 32 + slot * 8];
        }
#pragma unroll
        for (int m = 0; m < 4; ++m)
#pragma unroll
            for (int n = 0; n < 4; ++n)
                acc[m][n] = __builtin_amdgcn_mfma_f32_16x16x32_bf16(af[m], bfr[n], acc[m][n], 0, 0, 0);
    }

    // epilogue: C/D layout col=l&15, row=(l>>4)*4+reg  [m91-verified]
#pragma unroll
    for (int m = 0; m < 4; ++m) {
#pragma unroll
        for (int n = 0; n < 4; ++n) {
            int colg = n0 + wc * 64 + n * 16 + ll;
            float bvv = bias[colg];
#pragma unroll
            for (int j = 0; j < 4; ++j) {
                int li = m0 + wr * 64 + m * 16 + lh * 4 + j;
                float v = acc[m][n][j] + bvv;
                if (EPI == EPI_PLAIN) {
                    if (AMODE == AM_DENSE) {
                        if (addsrc) v += addsrc[(size_t)li * N + colg];
                        C[(size_t)li * N + colg] = v;
                    } else {
                        if (li < ne) C[(size_t)(base + li) * N + colg] = v;
                    }
                } else if (EPI == EPI_SILUMUL) {
                    if (AMODE == AM_DENSE || li < ne) {
                        size_t off = (AMODE == AM_DENSE) ? (size_t)li * N + colg
                                                         : (size_t)(base + li) * N + colg;
                        float a = addsrc[off];
                        float sil = a / (1.0f + __expf(-a));
                        C[off] = sil * v;   // in-place over addsrc is safe (same elem)
                    }
                } else {  // EPI_SCATTER, AM_GROUP
                    if (li < ne) {
                        int tok = tok_list[e * 2048 + li];
                        float wgt = comb[tok * 8 + e];
                        float* dst = (idx0[tok] == e) ? C : y1;
                        dst[(size_t)tok * N + colg] = wgt * v;
                    }
                }
            }
        }
    }
}

// ---------------------------------------------------------------- LayerNorm
__global__ __launch_bounds__(256) void ln_kernel(const float* __restrict__ x,
                                                 const float* __restrict__ w,
                                                 float* __restrict__ y) {
    __shared__ float red[4], red2[4];
    const int row = blockIdx.x;
    const int t = threadIdx.x;
    const float4* xr = (const float4*)(x + (size_t)row * DD);
    float4 v = xr[t];
    float s = v.x + v.y + v.z + v.w;
    float q = v.x * v.x + v.y * v.y + v.z * v.z + v.w * v.w;
    for (int o = 32; o; o >>= 1) { s += __shfl_down(s, o); q += __shfl_down(q, o); }
    if ((t & 63) == 0) { red[t >> 6] = s; red2[t >> 6] = q; }
    __syncthreads();
    float S = red[0] + red[1] + red[2] + red[3];
    float Q = red2[0] + red2[1] + red2[2] + red2[3];
    float mu = S * (1.0f / DD);
    float var = Q * (1.0f / DD) - mu * mu;
    float inv = rsqrtf(var + 1e-8f);
    const float4* wr = (const float4*)w;
    float4 wv = wr[t];
    float4 o4;
    o4.x = (v.x - mu) * inv * wv.x;
    o4.y = (v.y - mu) * inv * wv.y;
    o4.z = (v.z - mu) * inv * wv.z;
    o4.w = (v.w - mu) * inv * wv.w;
    ((float4*)(y + (size_t)row * DD))[t] = o4;
}

// ---------------------------------------------------------------- Attention
__global__ __launch_bounds__(256) void attn_kernel(const float* __restrict__ Q,
                                                   const float* __restrict__ Kk,
                                                   const float* __restrict__ V,
                                                   const float* __restrict__ pe,
                                                   const float* __restrict__ mask,
                                                   const int* __restrict__ sp_ptr,
                                                   float* __restrict__ O) {
    __shared__ float sq[64];
    __shared__ __align__(16) float kt[64][68];
    __shared__ float scores[SS];
    __shared__ float red[4];
    __shared__ float opart[4][64];
    const int bid = blockIdx.x;  // b*H*S + h*S + qs
    const int qs = bid & (SS - 1);
    const int h = (bid >> 10) & (HH - 1);
    const int b = bid >> 14;
    const int sp = sp_ptr[0];
    const int t = threadIdx.x;
    const size_t qoff = ((size_t)(b * SS + qs)) * DD + h * DKV;
    if (t < 64) sq[t] = Q[qoff + t];
    __syncthreads();
    const size_t kbase = (size_t)b * SS * DD + h * DKV;
    const size_t pbase = (size_t)h * SS * SS + (size_t)(sp + qs) * SS + sp;
    for (int kt0 = 0; kt0 < SS; kt0 += 64) {
        __syncthreads();
#pragma unroll
        for (int r = 0; r < 16; ++r) {
            int idx = t + 256 * r;
            int key = idx >> 6, d = idx & 63;
            kt[key][d] = Kk[kbase + (size_t)(kt0 + key) * DD + d];
        }
        __syncthreads();
        const int key = t >> 2, part = t & 3;
        const float* kr = &kt[key][part * 16];
        const float* qr = &sq[part * 16];
        float p = 0.f;
#pragma unroll
        for (int j = 0; j < 16; ++j) p += qr[j] * kr[j];
        p += __shfl_down(p, 2, 4);
        p += __shfl_down(p, 1, 4);
        if (part == 0) {
            int kg = kt0 + key;
            scores[kg] = p * 0.125f + pe[pbase + kg] + mask[(size_t)qs * SS + kg];
        }
    }
    __syncthreads();
    float m = -3.4e38f;
#pragma unroll
    for (int r = 0; r < 4; ++r) m = fmaxf(m, scores[t + 256 * r]);
    for (int o = 32; o; o >>= 1) m = fmaxf(m, __shfl_down(m, o));
    if ((t & 63) == 0) red[t >> 6] = m;
    __syncthreads();
    m = fmaxf(fmaxf(red[0], red[1]), fmaxf(red[2], red[3]));
    __syncthreads();
    float s = 0.f;
#pragma unroll
    for (int r = 0; r < 4; ++r) {
        float ev = __expf(scores[t + 256 * r] - m);
        scores[t + 256 * r] = ev;
        s += ev;
    }
    for (int o = 32; o; o >>= 1) s += __shfl_down(s, o);
    if ((t & 63) == 0) red[t >> 6] = s;
    __syncthreads();
    s = red[0] + red[1] + red[2] + red[3];
    const float inv = 1.0f / s;
    const int dv = t & 63, seg = t >> 6;
    const size_t vbase = (size_t)b * SS * DD + h * DKV + dv;
    float acc = 0.f;
    for (int key = seg * 256; key < seg * 256 + 256; ++key)
        acc += scores[key] * V[vbase + (size_t)key * DD];
    opart[seg][dv] = acc;
    __syncthreads();
    if (t < 64) {
        float ov = (opart[0][t] + opart[1][t] + opart[2][t] + opart[3][t]) * inv;
        O[qoff + t] = ov;
    }
}

// ---------------------------------------------------------------- Gating (f32 path)
__global__ __launch_bounds__(64) void gate_kernel(const float* __restrict__ hn,
                                                  const float* __restrict__ gw,
                                                  const float* __restrict__ gb,
                                                  float* __restrict__ comb,
                                                  int* __restrict__ idx0,
                                                  int* __restrict__ cnt,
                                                  int* __restrict__ tok_list) {
    __shared__ float lg[8];
    const int tok = blockIdx.x;
    const int lane = threadIdx.x;
    const int e = lane >> 3, chunk = lane & 7;
    const float* hr = hn + (size_t)tok * DD + chunk * 128;
    const float* gr = gw + (size_t)e * DD + chunk * 128;
    float p = 0.f;
    for (int j = 0; j < 128; ++j) p += hr[j] * gr[j];
    p += __shfl_down(p, 4, 8);
    p += __shfl_down(p, 2, 8);
    p += __shfl_down(p, 1, 8);
    if (chunk == 0) lg[e] = p + gb[e];
    __syncthreads();
    if (lane == 0) {
        float mx = lg[0];
        for (int i = 1; i < 8; ++i) mx = fmaxf(mx, lg[i]);
        float pr[8]; float ssum = 0.f;
        for (int i = 0; i < 8; ++i) { pr[i] = __expf(lg[i] - mx); ssum += pr[i]; }
        float is = 1.0f / ssum;
        for (int i = 0; i < 8; ++i) pr[i] *= is;
        int i1 = 0;
        for (int i = 1; i < 8; ++i) if (pr[i] > pr[i1]) i1 = i;
        int i2 = -1;
        for (int i = 0; i < 8; ++i) { if (i == i1) continue; if (i2 < 0 || pr[i] > pr[i2]) i2 = i; }
        float w0 = pr[i1], w1 = pr[i2];
        float nrm = 1.0f / (w0 + w1 + 1e-20f);
        w0 *= nrm; w1 *= nrm;
        for (int i = 0; i < 8; ++i) comb[tok * 8 + i] = 0.0f;
        comb[tok * 8 + i1] = w0;
        comb[tok * 8 + i2] = w1;
        idx0[tok] = i1;
        int s1 = atomicAdd(&cnt[i1], 1); tok_list[i1 * 2048 + s1] = tok;
        int s2 = atomicAdd(&cnt[i2], 1); tok_list[i2 * 2048 + s2] = tok;
    }
}

__global__ void init_cnt(int* cnt) { if (threadIdx.x < 8) cnt[threadIdx.x] = 0; }

__global__ void prefix_kernel(const int* __restrict__ cnt, int* __restrict__ offs) {
    if (threadIdx.x == 0) {
        int a = 0;
        for (int e = 0; e < 8; ++e) { offs[e] = a; a += cnt[e]; }
    }
}

// ---------------------------------------------------------------- Final sum
__global__ __launch_bounds__(256) void final_kernel(const float* __restrict__ x2,
                                                    const float* __restrict__ y0,
                                                    const float* __restrict__ y1,
                                                    const float* __restrict__ sh,
                                                    float* __restrict__ out) {
    size_t i = (size_t)blockIdx.x * 256 + threadIdx.x;
    float4 a = ((const float4*)x2)[i];
    float4 b = ((const float4*)y0)[i];
    float4 c = ((const float4*)y1)[i];
    float4 d = ((const float4*)sh)[i];
    float4 o;
    o.x = a.x + b.x + c.x + d.x;
    o.y = a.y + b.y + c.y + d.y;
    o.z = a.z + b.z + c.z + d.z;
    o.w = a.w + b.w + c.w + d.w;
    ((float4*)out)[i] = o;
}

extern "C" void kernel_launch(void* const* d_in, const int* in_sizes, int n_in,
                              void* d_out, int out_size, void* d_ws, size_t ws_size,
                              hipStream_t stream) {
    const float* x   = (const float*)d_in[0];
    const int*   sp  = (const int*)d_in[1];
    const float* mask= (const float*)d_in[2];
    const float* pe  = (const float*)d_in[3];
    const float* anw = (const float*)d_in[4];
    const float* fnw = (const float*)d_in[5];
    const float* wq  = (const float*)d_in[6];  const float* bq  = (const float*)d_in[7];
    const float* wk  = (const float*)d_in[8];  const float* bk  = (const float*)d_in[9];
    const float* wv  = (const float*)d_in[10]; const float* bv  = (const float*)d_in[11];
    const float* wo  = (const float*)d_in[12]; const float* bo  = (const float*)d_in[13];
    const float* gw  = (const float*)d_in[14]; const float* gb  = (const float*)d_in[15];
    const float* ew1 = (const float*)d_in[16]; const float* eb1 = (const float*)d_in[17];
    const float* ew2 = (const float*)d_in[18]; const float* eb2 = (const float*)d_in[19];
    const float* ew3 = (const float*)d_in[20]; const float* eb3 = (const float*)d_in[21];
    const float* sw1 = (const float*)d_in[22]; const float* sb1 = (const float*)d_in[23];
    const float* sw2 = (const float*)d_in[24]; const float* sb2 = (const float*)d_in[25];
    const float* sw3 = (const float*)d_in[26]; const float* sb3 = (const float*)d_in[27];

    float* ws = (float*)d_ws;
    const size_t M2 = (size_t)2048 * 1024;  // 2M floats (8MB) per slot
    // s0: xn -> o -> y0 | s1: q -> hn | s2: k -> y1 | s3: v -> sh | s4: x2
    // s5..s8: amid (8M floats, 32MB; routed a/mid then shared a/mid) | small after
    float* xn   = ws;
    float* q    = ws + 1 * M2;
    float* kbuf = ws + 2 * M2;
    float* vbuf = ws + 3 * M2;
    float* x2   = ws + 4 * M2;
    float* amid = ws + 5 * M2;
    float* small= ws + 9 * M2;
    float* comb = small;                  // 2048*8
    int* idx0   = (int*)(small + 16384);  // 2048
    int* cnt    = idx0 + 2048;            // 8
    int* offs   = cnt + 8;                // 8
    int* tok_list = offs + 8;             // 8*2048
    float* o   = xn;
    float* hn  = q;
    float* y0  = xn;
    float* y1  = kbuf;
    float* sh  = vbuf;

    // 1. attn layernorm
    ln_kernel<<<2048, 256, 0, stream>>>(x, anw, xn);
    // 2. QKV projections (bf16 MFMA)
    dim3 g_d(8, 16);
    mgemm<EPI_PLAIN, AM_DENSE><<<g_d, 256, 0, stream>>>(xn, wq, bq, nullptr, q, 2048, 1024, 1024,
        nullptr, nullptr, nullptr, nullptr, nullptr, nullptr);
    mgemm<EPI_PLAIN, AM_DENSE><<<g_d, 256, 0, stream>>>(xn, wk, bk, nullptr, kbuf, 2048, 1024, 1024,
        nullptr, nullptr, nullptr, nullptr, nullptr, nullptr);
    mgemm<EPI_PLAIN, AM_DENSE><<<g_d, 256, 0, stream>>>(xn, wv, bv, nullptr, vbuf, 2048, 1024, 1024,
        nullptr, nullptr, nullptr, nullptr, nullptr, nullptr);
    // 3. attention (f32, writes o)
    attn_kernel<<<BB * HH * SS, 256, 0, stream>>>(q, kbuf, vbuf, pe, mask, sp, o);
    // 4. output projection + residual
    mgemm<EPI_PLAIN, AM_DENSE><<<g_d, 256, 0, stream>>>(o, wo, bo, x, x2, 2048, 1024, 1024,
        nullptr, nullptr, nullptr, nullptr, nullptr, nullptr);
    // 5. ffn layernorm (f32 hn, also feeds gate)
    ln_kernel<<<2048, 256, 0, stream>>>(x2, fnw, hn);
    // 6. gating + token bucketing
    init_cnt<<<1, 64, 0, stream>>>(cnt);
    gate_kernel<<<2048, 64, 0, stream>>>(hn, gw, gb, comb, idx0, cnt, tok_list);
    prefix_kernel<<<1, 64, 0, stream>>>(cnt, offs);
    // 7. routed experts: a = gather(hn)@ew1+eb1 (grouped rows)
    mgemm<EPI_PLAIN, AM_GATHER><<<dim3(16, 16, 8), 256, 0, stream>>>(hn, ew1, eb1, nullptr, amid,
        2048, FF, 1024, tok_list, cnt, offs, nullptr, nullptr, nullptr);
    // 8. routed experts: mid = silu(a) * (gather(hn)@ew3+eb3), in-place over amid
    mgemm<EPI_SILUMUL, AM_GATHER><<<dim3(16, 16, 8), 256, 0, stream>>>(hn, ew3, eb3, amid, amid,
        2048, FF, 1024, tok_list, cnt, offs, nullptr, nullptr, nullptr);
    // 9. routed experts: y = comb * (mid@ew2+eb2), scattered to y0/y1 by rank
    mgemm<EPI_SCATTER, AM_GROUP><<<dim3(8, 16, 8), 256, 0, stream>>>(amid, ew2, eb2, nullptr, y0,
        2048, DD, FF, tok_list, cnt, offs, comb, idx0, y1);
    // 10. shared expert: a_s = hn@sw1+sb1 ; mid_s = silu(a_s)*(hn@sw3+sb3) in-place
    mgemm<EPI_PLAIN, AM_DENSE><<<dim3(32, 16), 256, 0, stream>>>(hn, sw1, sb1, nullptr, amid,
        2048, FSH2, 1024, nullptr, nullptr, nullptr, nullptr, nullptr, nullptr);
    mgemm<EPI_SILUMUL, AM_DENSE><<<dim3(32, 16), 256, 0, stream>>>(hn, sw3, sb3, amid, amid,
        2048, FSH2, 1024, nullptr, nullptr, nullptr, nullptr, nullptr, nullptr);
    // 11. shared expert out
    mgemm<EPI_PLAIN, AM_DENSE><<<g_d, 256, 0, stream>>>(amid, sw2, sb2, nullptr, sh,
        2048, DD, FSH2, nullptr, nullptr, nullptr, nullptr, nullptr, nullptr);
    // 12. out = x2 + y0 + y1 + shared
    final_kernel<<<2048, 256, 0, stream>>>(x2, y0, y1, sh, (float*)d_out);
}

// Round 3
// 936.719 us; speedup vs baseline: 2.8445x; 1.7145x over previous
//
#include <hip/hip_runtime.h>
#include <hip/hip_bf16.h>

// Shapes (fixed by the problem)
#define BB 2
#define SS 1024
#define DD 1024
#define HH 16
#define DKV 64
#define EE 8
#define FF 2048
#define FSH2 4096

typedef __attribute__((ext_vector_type(8))) short bf16x8;   // 8 bf16 = 4 VGPR (MFMA A/B frag)
typedef __attribute__((ext_vector_type(4))) float f32x4;    // MFMA C/D frag

// epilogue modes
#define EPI_PLAIN 0
#define EPI_SILUMUL 1
#define EPI_SCATTER 2
// A-row modes
#define AM_DENSE 0
#define AM_GATHER 1
#define AM_GROUP 2

__device__ inline unsigned pack_bf2(float lo, float hi) {
    __hip_bfloat162 h = __float22bfloat162_rn(float2{lo, hi});
    union { __hip_bfloat162 h2; unsigned u; } c; c.h2 = h; return c.u;
}
__device__ inline unsigned short bf16_1(float x) {
    union { __hip_bfloat16 b; unsigned short u; } c;
    c.b = __float2bfloat16(x); return c.u;
}

// ------------------------------------------------------------------
// bf16-MFMA GEMM, 128x128 tile, BK=32, 256 threads (4 waves as 2x2).
// ------------------------------------------------------------------
template<int EPI, int AMODE>
__global__ __launch_bounds__(256, 2) void mgemm(
    const float* __restrict__ A, const float* __restrict__ W,
    const float* __restrict__ bias, const float* __restrict__ addsrc,
    float* __restrict__ C, int M, int N, int K,
    const int* __restrict__ tok_list, const int* __restrict__ cnt,
    const int* __restrict__ offs, const float* __restrict__ comb,
    const int* __restrict__ idx0, float* __restrict__ y1)
{
    __shared__ __align__(16) unsigned short As[128 * 40];
    __shared__ __align__(16) unsigned short Bs[128 * 32];
    __shared__ int rows_s[128];
    const int t = threadIdx.x;
    const int e = (AMODE != AM_DENSE) ? blockIdx.z : 0;
    int ne = M, base = 0;
    if (AMODE != AM_DENSE) {
        ne = cnt[e];
        base = offs[e];
        if ((int)blockIdx.y * 128 >= ne) return;   // uniform exit, before any barrier
        W += (size_t)e * K * N;
        bias += (size_t)e * N;
    }
    const int m0 = blockIdx.y * 128;
    const int n0 = blockIdx.x * 128;
    if (AMODE == AM_GATHER) {
        if (t < 128) {
            int li = m0 + t; if (li >= ne) li = ne - 1;
            rows_s[t] = tok_list[e * 2048 + li];
        }
        __syncthreads();
    }
    const int ar = t >> 1;
    const int ac = (t & 1) * 16;
    const int bn = t & 127;
    const int bkp = (t >> 7) * 8;
    long arow;
    if (AMODE == AM_DENSE) arow = m0 + ar;
    else if (AMODE == AM_GATHER) arow = rows_s[ar];
    else { int li = m0 + ar; if (li >= ne) li = ne - 1; arow = base + li; }
    const float* Ap = A + (size_t)arow * K + ac;
    const float* Wcol = W + n0 + bn;
    const int l = t & 63, w = t >> 6;
    const int wr = w >> 1, wc = w & 1;
    const int lh = l >> 4, ll = l & 15;
    f32x4 acc[4][4];
#pragma unroll
    for (int i = 0; i < 4; ++i)
#pragma unroll
        for (int j = 0; j < 4; ++j) acc[i][j] = f32x4{0.f, 0.f, 0.f, 0.f};

    for (int k0 = 0; k0 < K; k0 += 32) {
        const float4* ap4 = (const float4*)(Ap + k0);
        float4 a0 = ap4[0], a1 = ap4[1], a2 = ap4[2], a3 = ap4[3];
        const float* wp = Wcol + (size_t)(k0 + 2 * bkp) * N;
        float bv[16];
#pragma unroll
        for (int j = 0; j < 16; ++j) bv[j] = wp[(size_t)j * N];
        __syncthreads();
        uint4 aw0, aw1;
        aw0.x = pack_bf2(a0.x, a0.y); aw0.y = pack_bf2(a0.z, a0.w);
        aw0.z = pack_bf2(a1.x, a1.y); aw0.w = pack_bf2(a1.z, a1.w);
        aw1.x = pack_bf2(a2.x, a2.y); aw1.y = pack_bf2(a2.z, a2.w);
        aw1.z = pack_bf2(a3.x, a3.y); aw1.w = pack_bf2(a3.z, a3.w);
        *(uint4*)&As[ar * 40 + ac] = aw0;
        *(uint4*)&As[ar * 40 + ac + 8] = aw1;
        uint4 bw0, bw1;
        bw0.x = pack_bf2(bv[0], bv[1]);  bw0.y = pack_bf2(bv[2], bv[3]);
        bw0.z = pack_bf2(bv[4], bv[5]);  bw0.w = pack_bf2(bv[6], bv[7]);
        bw1.x = pack_bf2(bv[8], bv[9]);  bw1.y = pack_bf2(bv[10], bv[11]);
        bw1.z = pack_bf2(bv[12], bv[13]); bw1.w = pack_bf2(bv[14], bv[15]);
        const int s0 = ((bkp >> 2) + 0) ^ (bn & 3);
        const int s1 = ((bkp >> 2) + 1) ^ (bn & 3);
        *(uint4*)&Bs[bn * 32 + s0 * 8] = bw0;
        *(uint4*)&Bs[bn * 32 + s1 * 8] = bw1;
        __syncthreads();
        bf16x8 af[4], bfr[4];
#pragma unroll
        for (int m = 0; m < 4; ++m) {
            int row = wr * 64 + m * 16 + ll;
            af[m] = *(const bf16x8*)&As[row * 40 + lh * 8];
        }
#pragma unroll
        for (int n = 0; n < 4; ++n) {
            int col = wc * 64 + n * 16 + ll;
            int slot = lh ^ (col & 3);
            bfr[n] = *(const bf16x8*)&Bs[col * 32 + slot * 8];
        }
#pragma unroll
        for (int m = 0; m < 4; ++m)
#pragma unroll
            for (int n = 0; n < 4; ++n)
                acc[m][n] = __builtin_amdgcn_mfma_f32_16x16x32_bf16(af[m], bfr[n], acc[m][n], 0, 0, 0);
    }

#pragma unroll
    for (int m = 0; m < 4; ++m) {
#pragma unroll
        for (int n = 0; n < 4; ++n) {
            int colg = n0 + wc * 64 + n * 16 + ll;
            float bvv = bias[colg];
#pragma unroll
            for (int j = 0; j < 4; ++j) {
                int li = m0 + wr * 64 + m * 16 + lh * 4 + j;
                float v = acc[m][n][j] + bvv;
                if (EPI == EPI_PLAIN) {
                    if (AMODE == AM_DENSE) {
                        if (addsrc) v += addsrc[(size_t)li * N + colg];
                        C[(size_t)li * N + colg] = v;
                    } else {
                        if (li < ne) C[(size_t)(base + li) * N + colg] = v;
                    }
                } else if (EPI == EPI_SILUMUL) {
                    if (AMODE == AM_DENSE || li < ne) {
                        size_t off = (AMODE == AM_DENSE) ? (size_t)li * N + colg
                                                         : (size_t)(base + li) * N + colg;
                        float a = addsrc[off];
                        float sil = a / (1.0f + __expf(-a));
                        C[off] = sil * v;
                    }
                } else {
                    if (li < ne) {
                        int tok = tok_list[e * 2048 + li];
                        float wgt = comb[tok * 8 + e];
                        float* dst = (idx0[tok] == e) ? C : y1;
                        dst[(size_t)tok * N + colg] = wgt * v;
                    }
                }
            }
        }
    }
}

// ---------------------------------------------------------------- LayerNorm
__global__ __launch_bounds__(256) void ln_kernel(const float* __restrict__ x,
                                                 const float* __restrict__ w,
                                                 float* __restrict__ y) {
    __shared__ float red[4], red2[4];
    const int row = blockIdx.x;
    const int t = threadIdx.x;
    const float4* xr = (const float4*)(x + (size_t)row * DD);
    float4 v = xr[t];
    float s = v.x + v.y + v.z + v.w;
    float q = v.x * v.x + v.y * v.y + v.z * v.z + v.w * v.w;
    for (int o = 32; o; o >>= 1) { s += __shfl_down(s, o); q += __shfl_down(q, o); }
    if ((t & 63) == 0) { red[t >> 6] = s; red2[t >> 6] = q; }
    __syncthreads();
    float S = red[0] + red[1] + red[2] + red[3];
    float Q = red2[0] + red2[1] + red2[2] + red2[3];
    float mu = S * (1.0f / DD);
    float var = Q * (1.0f / DD) - mu * mu;
    float inv = rsqrtf(var + 1e-8f);
    const float4* wr = (const float4*)w;
    float4 wv = wr[t];
    float4 o4;
    o4.x = (v.x - mu) * inv * wv.x;
    o4.y = (v.y - mu) * inv * wv.y;
    o4.z = (v.z - mu) * inv * wv.z;
    o4.w = (v.w - mu) * inv * wv.w;
    ((float4*)(y + (size_t)row * DD))[t] = o4;
}

// ---------------------------------------------------------------- MFMA flash attention
// Block: 256 thr / 4 waves. Q-tile 128 rows (wave w owns rows w*32..+32).
// KV tiles of 64 staged in LDS bf16: K [key][dim] XOR-swizzled, V transposed
// [vd][key] pair-packed + swizzled. Online softmax; P bounced via per-wave LDS.
__global__ __launch_bounds__(256) void attn_mfma(const float* __restrict__ Q,
                                                 const float* __restrict__ Kk,
                                                 const float* __restrict__ V,
                                                 const float* __restrict__ pe,
                                                 const float* __restrict__ mask,
                                                 const int* __restrict__ sp_ptr,
                                                 float* __restrict__ O) {
    __shared__ __align__(16) unsigned short Kt[64 * 64];     // 8 KB
    __shared__ __align__(16) unsigned short Vt[64 * 64];     // 8 KB, transposed
    __shared__ __align__(16) unsigned short Pl[4][32 * 64];  // 16 KB, per-wave P
    const int t = threadIdx.x;
    const int w = t >> 6, l = t & 63;
    const int ll = l & 15, lh = l >> 4;
    const int bh = blockIdx.y;
    const int b = bh >> 4, h = bh & 15;
    const int q0 = blockIdx.x * 128;
    const int sp = sp_ptr[0];

    // Q fragments (scaled by 1/8), rows q0 + w*32 + m*16 + ll
    bf16x8 qf[2][2];
#pragma unroll
    for (int m = 0; m < 2; ++m) {
        const float* qp = Q + (size_t)(b * SS + q0 + w * 32 + m * 16 + ll) * DD + h * 64 + lh * 8;
#pragma unroll
        for (int kk = 0; kk < 2; ++kk) {
            float4 x0 = *(const float4*)(qp + kk * 32);
            float4 x1 = *(const float4*)(qp + kk * 32 + 4);
            uint4 u;
            u.x = pack_bf2(x0.x * 0.125f, x0.y * 0.125f);
            u.y = pack_bf2(x0.z * 0.125f, x0.w * 0.125f);
            u.z = pack_bf2(x1.x * 0.125f, x1.y * 0.125f);
            u.w = pack_bf2(x1.z * 0.125f, x1.w * 0.125f);
            qf[m][kk] = *(bf16x8*)&u;
        }
    }
    f32x4 oacc[2][4];
#pragma unroll
    for (int m = 0; m < 2; ++m)
#pragma unroll
        for (int n = 0; n < 4; ++n) oacc[m][n] = f32x4{0.f, 0.f, 0.f, 0.f};
    float mrun[2][4], lrun[2][4];
#pragma unroll
    for (int m = 0; m < 2; ++m)
#pragma unroll
        for (int j = 0; j < 4; ++j) { mrun[m][j] = -3.0e38f; lrun[m][j] = 0.f; }

    const size_t pebase = (size_t)h * SS * SS + (size_t)sp;

    for (int kt0 = 0; kt0 < SS; kt0 += 64) {
        __syncthreads();   // previous iteration's LDS consumers done
        // ---- stage K tile: [key][dim] bf16, swizzle byte ^= (key&7)<<4
        {
            const int key = t >> 2, dg = (t & 3) * 16;
            const float* kp = Kk + (size_t)(b * SS + kt0 + key) * DD + h * 64 + dg;
            float4 k0 = *(const float4*)kp, k1 = *(const float4*)(kp + 4);
            float4 k2 = *(const float4*)(kp + 8), k3 = *(const float4*)(kp + 12);
            uint4 u0, u1;
            u0.x = pack_bf2(k0.x, k0.y); u0.y = pack_bf2(k0.z, k0.w);
            u0.z = pack_bf2(k1.x, k1.y); u0.w = pack_bf2(k1.z, k1.w);
            u1.x = pack_bf2(k2.x, k2.y); u1.y = pack_bf2(k2.z, k2.w);
            u1.z = pack_bf2(k3.x, k3.y); u1.w = pack_bf2(k3.z, k3.w);
            const int sw = (key & 7) << 4;
            *(uint4*)((char*)Kt + key * 128 + ((dg * 2) ^ sw)) = u0;
            *(uint4*)((char*)Kt + key * 128 + ((dg * 2 + 16) ^ sw)) = u1;
        }
        // ---- stage V tile transposed: [vd][key], u32 packs key-pair
        {
            const int kp2 = t & 31, vg = (t >> 5) * 8;
            const float* vp0 = V + (size_t)(b * SS + kt0 + 2 * kp2) * DD + h * 64 + vg;
            const float* vp1 = vp0 + DD;
            float4 a0 = *(const float4*)vp0, a1 = *(const float4*)(vp0 + 4);
            float4 b0 = *(const float4*)vp1, b1 = *(const float4*)(vp1 + 4);
            float va[8] = {a0.x, a0.y, a0.z, a0.w, a1.x, a1.y, a1.z, a1.w};
            float vb[8] = {b0.x, b0.y, b0.z, b0.w, b1.x, b1.y, b1.z, b1.w};
#pragma unroll
            for (int j = 0; j < 8; ++j) {
                int vd = vg + j;
                unsigned u = pack_bf2(va[j], vb[j]);
                *(unsigned*)((char*)Vt + vd * 128 + ((kp2 * 4) ^ ((vd & 7) << 4))) = u;
            }
        }
        __syncthreads();
        // ---- QK^T: sc[m][n], row q = m*16+lh*4+j, col key = n*16+ll
        f32x4 sc[2][4];
#pragma unroll
        for (int m = 0; m < 2; ++m)
#pragma unroll
            for (int n = 0; n < 4; ++n) sc[m][n] = f32x4{0.f, 0.f, 0.f, 0.f};
#pragma unroll
        for (int n = 0; n < 4; ++n) {
            const int key = n * 16 + ll;
            const int sw = (key & 7) << 4;
#pragma unroll
            for (int kk = 0; kk < 2; ++kk) {
                bf16x8 kf = *(const bf16x8*)((char*)Kt + key * 128 + ((kk * 64 + lh * 16) ^ sw));
#pragma unroll
                for (int m = 0; m < 2; ++m)
                    sc[m][n] = __builtin_amdgcn_mfma_f32_16x16x32_bf16(qf[m][kk], kf, sc[m][n], 0, 0, 0);
            }
        }
        // ---- + pe + mask
#pragma unroll
        for (int m = 0; m < 2; ++m)
#pragma unroll
            for (int j = 0; j < 4; ++j) {
                const int qrow = q0 + w * 32 + m * 16 + lh * 4 + j;
                const float* per = pe + pebase + (size_t)(sp + qrow) * SS + kt0 + ll;
                const float* mar = mask + (size_t)qrow * SS + kt0 + ll;
#pragma unroll
                for (int n = 0; n < 4; ++n)
                    sc[m][n][j] += per[n * 16] + mar[n * 16];
            }
        // ---- online softmax (per q-row: reduce over n in-reg, over ll via shfl_xor)
#pragma unroll
        for (int m = 0; m < 2; ++m)
#pragma unroll
            for (int j = 0; j < 4; ++j) {
                float mx = fmaxf(fmaxf(sc[m][0][j], sc[m][1][j]), fmaxf(sc[m][2][j], sc[m][3][j]));
#pragma unroll
                for (int o = 1; o < 16; o <<= 1) mx = fmaxf(mx, __shfl_xor(mx, o));
                float mnew = fmaxf(mrun[m][j], mx);
                float corr = __expf(mrun[m][j] - mnew);
                mrun[m][j] = mnew;
                float ssum = 0.f;
#pragma unroll
                for (int n = 0; n < 4; ++n) {
                    float p = __expf(sc[m][n][j] - mnew);
                    sc[m][n][j] = p;
                    ssum += p;
                }
#pragma unroll
                for (int o = 1; o < 16; o <<= 1) ssum += __shfl_xor(ssum, o);
                lrun[m][j] = lrun[m][j] * corr + ssum;
#pragma unroll
                for (int n = 0; n < 4; ++n) oacc[m][n][j] *= corr;
            }
        // ---- P -> bf16 -> per-wave LDS (swizzle on q-row)
#pragma unroll
        for (int m = 0; m < 2; ++m)
#pragma unroll
            for (int j = 0; j < 4; ++j) {
                const int lq = m * 16 + lh * 4 + j;
                const int sw = (lq & 7) << 4;
#pragma unroll
                for (int n = 0; n < 4; ++n) {
                    const int key = n * 16 + ll;
                    *(unsigned short*)((char*)Pl[w] + lq * 128 + ((key * 2) ^ sw)) =
                        bf16_1(sc[m][n][j]);
                }
            }
        asm volatile("s_waitcnt lgkmcnt(0)" ::: "memory");
        __builtin_amdgcn_sched_barrier(0);
        // ---- PV: O += P @ V
#pragma unroll
        for (int kk = 0; kk < 2; ++kk) {
            bf16x8 pf[2];
#pragma unroll
            for (int m = 0; m < 2; ++m) {
                const int lq = m * 16 + ll;
                pf[m] = *(const bf16x8*)((char*)Pl[w] + lq * 128 +
                                         ((kk * 64 + lh * 16) ^ ((lq & 7) << 4)));
            }
#pragma unroll
            for (int n = 0; n < 4; ++n) {
                const int vd = n * 16 + ll;
                bf16x8 vf = *(const bf16x8*)((char*)Vt + vd * 128 +
                                             ((kk * 64 + lh * 16) ^ ((vd & 7) << 4)));
#pragma unroll
                for (int m = 0; m < 2; ++m)
                    oacc[m][n] = __builtin_amdgcn_mfma_f32_16x16x32_bf16(pf[m], vf, oacc[m][n], 0, 0, 0);
            }
        }
    }
    // ---- epilogue
#pragma unroll
    for (int m = 0; m < 2; ++m)
#pragma unroll
        for (int j = 0; j < 4; ++j) {
            const int qrow = q0 + w * 32 + m * 16 + lh * 4 + j;
            const float invl = 1.0f / lrun[m][j];
#pragma unroll
            for (int n = 0; n < 4; ++n)
                O[(size_t)(b * SS + qrow) * DD + h * 64 + n * 16 + ll] = oacc[m][n][j] * invl;
        }
}

// ---------------------------------------------------------------- Gating (f32 path)
__global__ __launch_bounds__(64) void gate_kernel(const float* __restrict__ hn,
                                                  const float* __restrict__ gw,
                                                  const float* __restrict__ gb,
                                                  float* __restrict__ comb,
                                                  int* __restrict__ idx0,
                                                  int* __restrict__ cnt,
                                                  int* __restrict__ tok_list) {
    __shared__ float lg[8];
    const int tok = blockIdx.x;
    const int lane = threadIdx.x;
    const int e = lane >> 3, chunk = lane & 7;
    const float* hr = hn + (size_t)tok * DD + chunk * 128;
    const float* gr = gw + (size_t)e * DD + chunk * 128;
    float p = 0.f;
    for (int j = 0; j < 128; ++j) p += hr[j] * gr[j];
    p += __shfl_down(p, 4, 8);
    p += __shfl_down(p, 2, 8);
    p += __shfl_down(p, 1, 8);
    if (chunk == 0) lg[e] = p + gb[e];
    __syncthreads();
    if (lane == 0) {
        float mx = lg[0];
        for (int i = 1; i < 8; ++i) mx = fmaxf(mx, lg[i]);
        float pr[8]; float ssum = 0.f;
        for (int i = 0; i < 8; ++i) { pr[i] = __expf(lg[i] - mx); ssum += pr[i]; }
        float is = 1.0f / ssum;
        for (int i = 0; i < 8; ++i) pr[i] *= is;
        int i1 = 0;
        for (int i = 1; i < 8; ++i) if (pr[i] > pr[i1]) i1 = i;
        int i2 = -1;
        for (int i = 0; i < 8; ++i) { if (i == i1) continue; if (i2 < 0 || pr[i] > pr[i2]) i2 = i; }
        float w0 = pr[i1], w1 = pr[i2];
        float nrm = 1.0f / (w0 + w1 + 1e-20f);
        w0 *= nrm; w1 *= nrm;
        for (int i = 0; i < 8; ++i) comb[tok * 8 + i] = 0.0f;
        comb[tok * 8 + i1] = w0;
        comb[tok * 8 + i2] = w1;
        idx0[tok] = i1;
        int s1 = atomicAdd(&cnt[i1], 1); tok_list[i1 * 2048 + s1] = tok;
        int s2 = atomicAdd(&cnt[i2], 1); tok_list[i2 * 2048 + s2] = tok;
    }
}

__global__ void init_cnt(int* cnt) { if (threadIdx.x < 8) cnt[threadIdx.x] = 0; }

__global__ void prefix_kernel(const int* __restrict__ cnt, int* __restrict__ offs) {
    if (threadIdx.x == 0) {
        int a = 0;
        for (int e = 0; e < 8; ++e) { offs[e] = a; a += cnt[e]; }
    }
}

// ---------------------------------------------------------------- Final sum
__global__ __launch_bounds__(256) void final_kernel(const float* __restrict__ x2,
                                                    const float* __restrict__ y0,
                                                    const float* __restrict__ y1,
                                                    const float* __restrict__ sh,
                                                    float* __restrict__ out) {
    size_t i = (size_t)blockIdx.x * 256 + threadIdx.x;
    float4 a = ((const float4*)x2)[i];
    float4 b = ((const float4*)y0)[i];
    float4 c = ((const float4*)y1)[i];
    float4 d = ((const float4*)sh)[i];
    float4 o;
    o.x = a.x + b.x + c.x + d.x;
    o.y = a.y + b.y + c.y + d.y;
    o.z = a.z + b.z + c.z + d.z;
    o.w = a.w + b.w + c.w + d.w;
    ((float4*)out)[i] = o;
}

extern "C" void kernel_launch(void* const* d_in, const int* in_sizes, int n_in,
                              void* d_out, int out_size, void* d_ws, size_t ws_size,
                              hipStream_t stream) {
    const float* x   = (const float*)d_in[0];
    const int*   sp  = (const int*)d_in[1];
    const float* mask= (const float*)d_in[2];
    const float* pe  = (const float*)d_in[3];
    const float* anw = (const float*)d_in[4];
    const float* fnw = (const float*)d_in[5];
    const float* wq  = (const float*)d_in[6];  const float* bq  = (const float*)d_in[7];
    const float* wk  = (const float*)d_in[8];  const float* bk  = (const float*)d_in[9];
    const float* wv  = (const float*)d_in[10]; const float* bv  = (const float*)d_in[11];
    const float* wo  = (const float*)d_in[12]; const float* bo  = (const float*)d_in[13];
    const float* gw  = (const float*)d_in[14]; const float* gb  = (const float*)d_in[15];
    const float* ew1 = (const float*)d_in[16]; const float* eb1 = (const float*)d_in[17];
    const float* ew2 = (const float*)d_in[18]; const float* eb2 = (const float*)d_in[19];
    const float* ew3 = (const float*)d_in[20]; const float* eb3 = (const float*)d_in[21];
    const float* sw1 = (const float*)d_in[22]; const float* sb1 = (const float*)d_in[23];
    const float* sw2 = (const float*)d_in[24]; const float* sb2 = (const float*)d_in[25];
    const float* sw3 = (const float*)d_in[26]; const float* sb3 = (const float*)d_in[27];

    float* ws = (float*)d_ws;
    const size_t M2 = (size_t)2048 * 1024;
    float* xn   = ws;
    float* q    = ws + 1 * M2;
    float* kbuf = ws + 2 * M2;
    float* vbuf = ws + 3 * M2;
    float* x2   = ws + 4 * M2;
    float* amid = ws + 5 * M2;
    float* small= ws + 9 * M2;
    float* comb = small;
    int* idx0   = (int*)(small + 16384);
    int* cnt    = idx0 + 2048;
    int* offs   = cnt + 8;
    int* tok_list = offs + 8;
    float* o   = xn;
    float* hn  = q;
    float* y0  = xn;
    float* y1  = kbuf;
    float* sh  = vbuf;

    ln_kernel<<<2048, 256, 0, stream>>>(x, anw, xn);
    dim3 g_d(8, 16);
    mgemm<EPI_PLAIN, AM_DENSE><<<g_d, 256, 0, stream>>>(xn, wq, bq, nullptr, q, 2048, 1024, 1024,
        nullptr, nullptr, nullptr, nullptr, nullptr, nullptr);
    mgemm<EPI_PLAIN, AM_DENSE><<<g_d, 256, 0, stream>>>(xn, wk, bk, nullptr, kbuf, 2048, 1024, 1024,
        nullptr, nullptr, nullptr, nullptr, nullptr, nullptr);
    mgemm<EPI_PLAIN, AM_DENSE><<<g_d, 256, 0, stream>>>(xn, wv, bv, nullptr, vbuf, 2048, 1024, 1024,
        nullptr, nullptr, nullptr, nullptr, nullptr, nullptr);
    attn_mfma<<<dim3(SS / 128, BB * HH), 256, 0, stream>>>(q, kbuf, vbuf, pe, mask, sp, o);
    mgemm<EPI_PLAIN, AM_DENSE><<<g_d, 256, 0, stream>>>(o, wo, bo, x, x2, 2048, 1024, 1024,
        nullptr, nullptr, nullptr, nullptr, nullptr, nullptr);
    ln_kernel<<<2048, 256, 0, stream>>>(x2, fnw, hn);
    init_cnt<<<1, 64, 0, stream>>>(cnt);
    gate_kernel<<<2048, 64, 0, stream>>>(hn, gw, gb, comb, idx0, cnt, tok_list);
    prefix_kernel<<<1, 64, 0, stream>>>(cnt, offs);
    mgemm<EPI_PLAIN, AM_GATHER><<<dim3(16, 16, 8), 256, 0, stream>>>(hn, ew1, eb1, nullptr, amid,
        2048, FF, 1024, tok_list, cnt, offs, nullptr, nullptr, nullptr);
    mgemm<EPI_SILUMUL, AM_GATHER><<<dim3(16, 16, 8), 256, 0, stream>>>(hn, ew3, eb3, amid, amid,
        2048, FF, 1024, tok_list, cnt, offs, nullptr, nullptr, nullptr);
    mgemm<EPI_SCATTER, AM_GROUP><<<dim3(8, 16, 8), 256, 0, stream>>>(amid, ew2, eb2, nullptr, y0,
        2048, DD, FF, tok_list, cnt, offs, comb, idx0, y1);
    mgemm<EPI_PLAIN, AM_DENSE><<<dim3(32, 16), 256, 0, stream>>>(hn, sw1, sb1, nullptr, amid,
        2048, FSH2, 1024, nullptr, nullptr, nullptr, nullptr, nullptr, nullptr);
    mgemm<EPI_SILUMUL, AM_DENSE><<<dim3(32, 16), 256, 0, stream>>>(hn, sw3, sb3, amid, amid,
        2048, FSH2, 1024, nullptr, nullptr, nullptr, nullptr, nullptr, nullptr);
    mgemm<EPI_PLAIN, AM_DENSE><<<g_d, 256, 0, stream>>>(amid, sw2, sb2, nullptr, sh,
        2048, DD, FSH2, nullptr, nullptr, nullptr, nullptr, nullptr, nullptr);
    final_kernel<<<2048, 256, 0, stream>>>(x2, y0, y1, sh, (float*)d_out);
}

// Round 4
// 698.182 us; speedup vs baseline: 3.8163x; 1.3417x over previous
//
#include <hip/hip_runtime.h>
#include <hip/hip_bf16.h>

// Shapes (fixed by the problem)
#define BB 2
#define SS 1024
#define DD 1024
#define HH 16
#define DKV 64
#define EE 8
#define FF 2048
#define FSH2 4096

typedef __attribute__((ext_vector_type(8))) short bf16x8;   // 8 bf16 = 4 VGPR (MFMA A/B frag)
typedef __attribute__((ext_vector_type(4))) float f32x4;    // MFMA C/D frag

// epilogue modes
#define EPI_PLAIN 0
#define EPI_SILUMUL 1
#define EPI_SCATTER 2
// A-row modes
#define AM_DENSE 0
#define AM_GATHER 1
#define AM_GROUP 2

__device__ inline unsigned pack_bf2(float lo, float hi) {
    __hip_bfloat162 h = __float22bfloat162_rn(float2{lo, hi});
    union { __hip_bfloat162 h2; unsigned u; } c; c.h2 = h; return c.u;
}
__device__ inline unsigned short bf16_1(float x) {
    union { __hip_bfloat16 b; unsigned short u; } c;
    c.b = __float2bfloat16(x); return c.u;
}

// ------------------------------------------------------------------
// bf16-MFMA GEMM, 128x128 tile, BK=32, 256 threads (4 waves as 2x2).
// Software-pipelined: tile k+1 prefetched to regs during MFMA of tile k;
// raw s_barrier (no vmcnt drain) keeps the prefetch in flight.
// NSEL==3: blockIdx.z selects (W,bias,C) triple (QKV in one dispatch).
// ------------------------------------------------------------------
template<int EPI, int AMODE, int NSEL>
__global__ __launch_bounds__(256, 2) void mgemm(
    const float* __restrict__ A,
    const float* __restrict__ W0, const float* __restrict__ W1p, const float* __restrict__ W2p,
    const float* __restrict__ b0, const float* __restrict__ b1p, const float* __restrict__ b2p,
    const float* __restrict__ addsrc,
    float* __restrict__ C0, float* __restrict__ C1p, float* __restrict__ C2p,
    int M, int N, int K,
    const int* __restrict__ tok_list, const int* __restrict__ cnt,
    const int* __restrict__ offs, const float* __restrict__ comb,
    const int* __restrict__ idx0, float* __restrict__ y1)
{
    __shared__ __align__(16) unsigned short As[128 * 40];
    __shared__ __align__(16) unsigned short Bs[128 * 32];
    __shared__ int rows_s[128];
    const int t = threadIdx.x;
    const float* W = W0; const float* bias = b0; float* C = C0;
    if (NSEL == 3) {
        if (blockIdx.z == 1) { W = W1p; bias = b1p; C = C1p; }
        else if (blockIdx.z == 2) { W = W2p; bias = b2p; C = C2p; }
    }
    const int e = (AMODE != AM_DENSE) ? blockIdx.z : 0;
    int ne = M, base = 0;
    if (AMODE != AM_DENSE) {
        ne = cnt[e];
        base = offs[e];
        if ((int)blockIdx.y * 128 >= ne) return;   // uniform exit, before any barrier
        W += (size_t)e * K * N;
        bias += (size_t)e * N;
    }
    const int m0 = blockIdx.y * 128;
    const int n0 = blockIdx.x * 128;
    if (AMODE == AM_GATHER) {
        if (t < 128) {
            int li = m0 + t; if (li >= ne) li = ne - 1;
            rows_s[t] = tok_list[e * 2048 + li];
        }
        __syncthreads();
    }
    const int ar = t >> 1;
    const int ac = (t & 1) * 16;
    const int bn = t & 127;
    const int bkp = (t >> 7) * 8;
    long arow;
    if (AMODE == AM_DENSE) arow = m0 + ar;
    else if (AMODE == AM_GATHER) arow = rows_s[ar];
    else { int li = m0 + ar; if (li >= ne) li = ne - 1; arow = base + li; }
    const float* Ap = A + (size_t)arow * K + ac;
    const float* Wcol = W + n0 + bn;
    const int l = t & 63, w = t >> 6;
    const int wr = w >> 1, wc = w & 1;
    const int lh = l >> 4, ll = l & 15;
    f32x4 acc[4][4];
#pragma unroll
    for (int i = 0; i < 4; ++i)
#pragma unroll
        for (int j = 0; j < 4; ++j) acc[i][j] = f32x4{0.f, 0.f, 0.f, 0.f};

    const int NT = K >> 5;
    // ---- prologue: prefetch tile 0
    float4 pa0, pa1, pa2, pa3;
    float pb[16];
    {
        const float4* ap4 = (const float4*)Ap;
        pa0 = ap4[0]; pa1 = ap4[1]; pa2 = ap4[2]; pa3 = ap4[3];
        const float* wp = Wcol + (size_t)(2 * bkp) * N;
#pragma unroll
        for (int j = 0; j < 16; ++j) pb[j] = wp[(size_t)j * N];
    }
    for (int it = 0; it < NT; ++it) {
        // ---- convert + stage current tile (vmcnt waits inserted by compiler here)
        uint4 aw0, aw1;
        aw0.x = pack_bf2(pa0.x, pa0.y); aw0.y = pack_bf2(pa0.z, pa0.w);
        aw0.z = pack_bf2(pa1.x, pa1.y); aw0.w = pack_bf2(pa1.z, pa1.w);
        aw1.x = pack_bf2(pa2.x, pa2.y); aw1.y = pack_bf2(pa2.z, pa2.w);
        aw1.z = pack_bf2(pa3.x, pa3.y); aw1.w = pack_bf2(pa3.z, pa3.w);
        *(uint4*)&As[ar * 40 + ac] = aw0;
        *(uint4*)&As[ar * 40 + ac + 8] = aw1;
        uint4 bw0, bw1;
        bw0.x = pack_bf2(pb[0], pb[1]);  bw0.y = pack_bf2(pb[2], pb[3]);
        bw0.z = pack_bf2(pb[4], pb[5]);  bw0.w = pack_bf2(pb[6], pb[7]);
        bw1.x = pack_bf2(pb[8], pb[9]);  bw1.y = pack_bf2(pb[10], pb[11]);
        bw1.z = pack_bf2(pb[12], pb[13]); bw1.w = pack_bf2(pb[14], pb[15]);
        const int s0 = ((bkp >> 2) + 0) ^ (bn & 3);
        const int s1 = ((bkp >> 2) + 1) ^ (bn & 3);
        *(uint4*)&Bs[bn * 32 + s0 * 8] = bw0;
        *(uint4*)&Bs[bn * 32 + s1 * 8] = bw1;
        // ---- issue next tile's global loads (stay in flight across barriers/MFMA)
        if (it + 1 < NT) {
            const int k0 = (it + 1) << 5;
            const float4* ap4 = (const float4*)(Ap + k0);
            pa0 = ap4[0]; pa1 = ap4[1]; pa2 = ap4[2]; pa3 = ap4[3];
            const float* wp = Wcol + (size_t)(k0 + 2 * bkp) * N;
#pragma unroll
            for (int j = 0; j < 16; ++j) pb[j] = wp[(size_t)j * N];
        }
        // my ds_writes committed, then workgroup sync — NO vmcnt drain
        asm volatile("s_waitcnt lgkmcnt(0)\n\ts_barrier" ::: "memory");
        bf16x8 af[4], bfr[4];
#pragma unroll
        for (int m = 0; m < 4; ++m) {
            int row = wr * 64 + m * 16 + ll;
            af[m] = *(const bf16x8*)&As[row * 40 + lh * 8];
        }
#pragma unroll
        for (int n = 0; n < 4; ++n) {
            int col = wc * 64 + n * 16 + ll;
            int slot = lh ^ (col & 3);
            bfr[n] = *(const bf16x8*)&Bs[col * 32 + slot * 8];
        }
#pragma unroll
        for (int m = 0; m < 4; ++m)
#pragma unroll
            for (int n = 0; n < 4; ++n)
                acc[m][n] = __builtin_amdgcn_mfma_f32_16x16x32_bf16(af[m], bfr[n], acc[m][n], 0, 0, 0);
        // protect LDS before next iteration's overwrite — NO vmcnt drain
        asm volatile("s_barrier" ::: "memory");
    }

#pragma unroll
    for (int m = 0; m < 4; ++m) {
#pragma unroll
        for (int n = 0; n < 4; ++n) {
            int colg = n0 + wc * 64 + n * 16 + ll;
            float bvv = bias[colg];
#pragma unroll
            for (int j = 0; j < 4; ++j) {
                int li = m0 + wr * 64 + m * 16 + lh * 4 + j;
                float v = acc[m][n][j] + bvv;
                if (EPI == EPI_PLAIN) {
                    if (AMODE == AM_DENSE) {
                        if (addsrc) v += addsrc[(size_t)li * N + colg];
                        C[(size_t)li * N + colg] = v;
                    } else {
                        if (li < ne) C[(size_t)(base + li) * N + colg] = v;
                    }
                } else if (EPI == EPI_SILUMUL) {
                    if (AMODE == AM_DENSE || li < ne) {
                        size_t off = (AMODE == AM_DENSE) ? (size_t)li * N + colg
                                                         : (size_t)(base + li) * N + colg;
                        float a = addsrc[off];
                        float sil = a / (1.0f + __expf(-a));
                        C[off] = sil * v;
                    }
                } else {
                    if (li < ne) {
                        int tok = tok_list[e * 2048 + li];
                        float wgt = comb[tok * 8 + e];
                        float* dst = (idx0[tok] == e) ? C : y1;
                        dst[(size_t)tok * N + colg] = wgt * v;
                    }
                }
            }
        }
    }
}

// ---------------------------------------------------------------- LayerNorm
__global__ __launch_bounds__(256) void ln_kernel(const float* __restrict__ x,
                                                 const float* __restrict__ w,
                                                 float* __restrict__ y) {
    __shared__ float red[4], red2[4];
    const int row = blockIdx.x;
    const int t = threadIdx.x;
    const float4* xr = (const float4*)(x + (size_t)row * DD);
    float4 v = xr[t];
    float s = v.x + v.y + v.z + v.w;
    float q = v.x * v.x + v.y * v.y + v.z * v.z + v.w * v.w;
    for (int o = 32; o; o >>= 1) { s += __shfl_down(s, o); q += __shfl_down(q, o); }
    if ((t & 63) == 0) { red[t >> 6] = s; red2[t >> 6] = q; }
    __syncthreads();
    float S = red[0] + red[1] + red[2] + red[3];
    float Q = red2[0] + red2[1] + red2[2] + red2[3];
    float mu = S * (1.0f / DD);
    float var = Q * (1.0f / DD) - mu * mu;
    float inv = rsqrtf(var + 1e-8f);
    const float4* wr = (const float4*)w;
    float4 wv = wr[t];
    float4 o4;
    o4.x = (v.x - mu) * inv * wv.x;
    o4.y = (v.y - mu) * inv * wv.y;
    o4.z = (v.z - mu) * inv * wv.z;
    o4.w = (v.w - mu) * inv * wv.w;
    ((float4*)(y + (size_t)row * DD))[t] = o4;
}

// ---------------------------------------------------------------- MFMA flash attention
__global__ __launch_bounds__(256) void attn_mfma(const float* __restrict__ Q,
                                                 const float* __restrict__ Kk,
                                                 const float* __restrict__ V,
                                                 const float* __restrict__ pe,
                                                 const float* __restrict__ mask,
                                                 const int* __restrict__ sp_ptr,
                                                 float* __restrict__ O) {
    __shared__ __align__(16) unsigned short Kt[64 * 64];     // 8 KB
    __shared__ __align__(16) unsigned short Vt[64 * 64];     // 8 KB, transposed
    __shared__ __align__(16) unsigned short Pl[4][32 * 64];  // 16 KB, per-wave P
    const int t = threadIdx.x;
    const int w = t >> 6, l = t & 63;
    const int ll = l & 15, lh = l >> 4;
    const int bh = blockIdx.y;
    const int b = bh >> 4, h = bh & 15;
    const int q0 = blockIdx.x * 128;
    const int sp = sp_ptr[0];

    bf16x8 qf[2][2];
#pragma unroll
    for (int m = 0; m < 2; ++m) {
        const float* qp = Q + (size_t)(b * SS + q0 + w * 32 + m * 16 + ll) * DD + h * 64 + lh * 8;
#pragma unroll
        for (int kk = 0; kk < 2; ++kk) {
            float4 x0 = *(const float4*)(qp + kk * 32);
            float4 x1 = *(const float4*)(qp + kk * 32 + 4);
            uint4 u;
            u.x = pack_bf2(x0.x * 0.125f, x0.y * 0.125f);
            u.y = pack_bf2(x0.z * 0.125f, x0.w * 0.125f);
            u.z = pack_bf2(x1.x * 0.125f, x1.y * 0.125f);
            u.w = pack_bf2(x1.z * 0.125f, x1.w * 0.125f);
            qf[m][kk] = *(bf16x8*)&u;
        }
    }
    f32x4 oacc[2][4];
#pragma unroll
    for (int m = 0; m < 2; ++m)
#pragma unroll
        for (int n = 0; n < 4; ++n) oacc[m][n] = f32x4{0.f, 0.f, 0.f, 0.f};
    float mrun[2][4], lrun[2][4];
#pragma unroll
    for (int m = 0; m < 2; ++m)
#pragma unroll
        for (int j = 0; j < 4; ++j) { mrun[m][j] = -3.0e38f; lrun[m][j] = 0.f; }

    const size_t pebase = (size_t)h * SS * SS + (size_t)sp;

    for (int kt0 = 0; kt0 < SS; kt0 += 64) {
        __syncthreads();
        {
            const int key = t >> 2, dg = (t & 3) * 16;
            const float* kp = Kk + (size_t)(b * SS + kt0 + key) * DD + h * 64 + dg;
            float4 k0 = *(const float4*)kp, k1 = *(const float4*)(kp + 4);
            float4 k2 = *(const float4*)(kp + 8), k3 = *(const float4*)(kp + 12);
            uint4 u0, u1;
            u0.x = pack_bf2(k0.x, k0.y); u0.y = pack_bf2(k0.z, k0.w);
            u0.z = pack_bf2(k1.x, k1.y); u0.w = pack_bf2(k1.z, k1.w);
            u1.x = pack_bf2(k2.x, k2.y); u1.y = pack_bf2(k2.z, k2.w);
            u1.z = pack_bf2(k3.x, k3.y); u1.w = pack_bf2(k3.z, k3.w);
            const int sw = (key & 7) << 4;
            *(uint4*)((char*)Kt + key * 128 + ((dg * 2) ^ sw)) = u0;
            *(uint4*)((char*)Kt + key * 128 + ((dg * 2 + 16) ^ sw)) = u1;
        }
        {
            const int kp2 = t & 31, vg = (t >> 5) * 8;
            const float* vp0 = V + (size_t)(b * SS + kt0 + 2 * kp2) * DD + h * 64 + vg;
            const float* vp1 = vp0 + DD;
            float4 a0 = *(const float4*)vp0, a1 = *(const float4*)(vp0 + 4);
            float4 b0 = *(const float4*)vp1, b1 = *(const float4*)(vp1 + 4);
            float va[8] = {a0.x, a0.y, a0.z, a0.w, a1.x, a1.y, a1.z, a1.w};
            float vb[8] = {b0.x, b0.y, b0.z, b0.w, b1.x, b1.y, b1.z, b1.w};
#pragma unroll
            for (int j = 0; j < 8; ++j) {
                int vd = vg + j;
                unsigned u = pack_bf2(va[j], vb[j]);
                *(unsigned*)((char*)Vt + vd * 128 + ((kp2 * 4) ^ ((vd & 7) << 4))) = u;
            }
        }
        __syncthreads();
        f32x4 sc[2][4];
#pragma unroll
        for (int m = 0; m < 2; ++m)
#pragma unroll
            for (int n = 0; n < 4; ++n) sc[m][n] = f32x4{0.f, 0.f, 0.f, 0.f};
#pragma unroll
        for (int n = 0; n < 4; ++n) {
            const int key = n * 16 + ll;
            const int sw = (key & 7) << 4;
#pragma unroll
            for (int kk = 0; kk < 2; ++kk) {
                bf16x8 kf = *(const bf16x8*)((char*)Kt + key * 128 + ((kk * 64 + lh * 16) ^ sw));
#pragma unroll
                for (int m = 0; m < 2; ++m)
                    sc[m][n] = __builtin_amdgcn_mfma_f32_16x16x32_bf16(qf[m][kk], kf, sc[m][n], 0, 0, 0);
            }
        }
#pragma unroll
        for (int m = 0; m < 2; ++m)
#pragma unroll
            for (int j = 0; j < 4; ++j) {
                const int qrow = q0 + w * 32 + m * 16 + lh * 4 + j;
                const float* per = pe + pebase + (size_t)(sp + qrow) * SS + kt0 + ll;
                const float* mar = mask + (size_t)qrow * SS + kt0 + ll;
#pragma unroll
                for (int n = 0; n < 4; ++n)
                    sc[m][n][j] += per[n * 16] + mar[n * 16];
            }
#pragma unroll
        for (int m = 0; m < 2; ++m)
#pragma unroll
            for (int j = 0; j < 4; ++j) {
                float mx = fmaxf(fmaxf(sc[m][0][j], sc[m][1][j]), fmaxf(sc[m][2][j], sc[m][3][j]));
#pragma unroll
                for (int o = 1; o < 16; o <<= 1) mx = fmaxf(mx, __shfl_xor(mx, o));
                float mnew = fmaxf(mrun[m][j], mx);
                float corr = __expf(mrun[m][j] - mnew);
                mrun[m][j] = mnew;
                float ssum = 0.f;
#pragma unroll
                for (int n = 0; n < 4; ++n) {
                    float p = __expf(sc[m][n][j] - mnew);
                    sc[m][n][j] = p;
                    ssum += p;
                }
#pragma unroll
                for (int o = 1; o < 16; o <<= 1) ssum += __shfl_xor(ssum, o);
                lrun[m][j] = lrun[m][j] * corr + ssum;
#pragma unroll
                for (int n = 0; n < 4; ++n) oacc[m][n][j] *= corr;
            }
#pragma unroll
        for (int m = 0; m < 2; ++m)
#pragma unroll
            for (int j = 0; j < 4; ++j) {
                const int lq = m * 16 + lh * 4 + j;
                const int sw = (lq & 7) << 4;
#pragma unroll
                for (int n = 0; n < 4; ++n) {
                    const int key = n * 16 + ll;
                    *(unsigned short*)((char*)Pl[w] + lq * 128 + ((key * 2) ^ sw)) =
                        bf16_1(sc[m][n][j]);
                }
            }
        asm volatile("s_waitcnt lgkmcnt(0)" ::: "memory");
        __builtin_amdgcn_sched_barrier(0);
#pragma unroll
        for (int kk = 0; kk < 2; ++kk) {
            bf16x8 pf[2];
#pragma unroll
            for (int m = 0; m < 2; ++m) {
                const int lq = m * 16 + ll;
                pf[m] = *(const bf16x8*)((char*)Pl[w] + lq * 128 +
                                         ((kk * 64 + lh * 16) ^ ((lq & 7) << 4)));
            }
#pragma unroll
            for (int n = 0; n < 4; ++n) {
                const int vd = n * 16 + ll;
                bf16x8 vf = *(const bf16x8*)((char*)Vt + vd * 128 +
                                             ((kk * 64 + lh * 16) ^ ((vd & 7) << 4)));
#pragma unroll
                for (int m = 0; m < 2; ++m)
                    oacc[m][n] = __builtin_amdgcn_mfma_f32_16x16x32_bf16(pf[m], vf, oacc[m][n], 0, 0, 0);
            }
        }
    }
#pragma unroll
    for (int m = 0; m < 2; ++m)
#pragma unroll
        for (int j = 0; j < 4; ++j) {
            const int qrow = q0 + w * 32 + m * 16 + lh * 4 + j;
            const float invl = 1.0f / lrun[m][j];
#pragma unroll
            for (int n = 0; n < 4; ++n)
                O[(size_t)(b * SS + qrow) * DD + h * 64 + n * 16 + ll] = oacc[m][n][j] * invl;
        }
}

// ---------------------------------------------------------------- Gating (f32 path)
__global__ __launch_bounds__(64) void gate_kernel(const float* __restrict__ hn,
                                                  const float* __restrict__ gw,
                                                  const float* __restrict__ gb,
                                                  float* __restrict__ comb,
                                                  int* __restrict__ idx0,
                                                  int* __restrict__ cnt,
                                                  int* __restrict__ tok_list) {
    __shared__ float lg[8];
    const int tok = blockIdx.x;
    const int lane = threadIdx.x;
    const int e = lane >> 3, chunk = lane & 7;
    const float* hr = hn + (size_t)tok * DD + chunk * 128;
    const float* gr = gw + (size_t)e * DD + chunk * 128;
    float p = 0.f;
    for (int j = 0; j < 128; ++j) p += hr[j] * gr[j];
    p += __shfl_down(p, 4, 8);
    p += __shfl_down(p, 2, 8);
    p += __shfl_down(p, 1, 8);
    if (chunk == 0) lg[e] = p + gb[e];
    __syncthreads();
    if (lane == 0) {
        float mx = lg[0];
        for (int i = 1; i < 8; ++i) mx = fmaxf(mx, lg[i]);
        float pr[8]; float ssum = 0.f;
        for (int i = 0; i < 8; ++i) { pr[i] = __expf(lg[i] - mx); ssum += pr[i]; }
        float is = 1.0f / ssum;
        for (int i = 0; i < 8; ++i) pr[i] *= is;
        int i1 = 0;
        for (int i = 1; i < 8; ++i) if (pr[i] > pr[i1]) i1 = i;
        int i2 = -1;
        for (int i = 0; i < 8; ++i) { if (i == i1) continue; if (i2 < 0 || pr[i] > pr[i2]) i2 = i; }
        float w0 = pr[i1], w1 = pr[i2];
        float nrm = 1.0f / (w0 + w1 + 1e-20f);
        w0 *= nrm; w1 *= nrm;
        for (int i = 0; i < 8; ++i) comb[tok * 8 + i] = 0.0f;
        comb[tok * 8 + i1] = w0;
        comb[tok * 8 + i2] = w1;
        idx0[tok] = i1;
        int s1 = atomicAdd(&cnt[i1], 1); tok_list[i1 * 2048 + s1] = tok;
        int s2 = atomicAdd(&cnt[i2], 1); tok_list[i2 * 2048 + s2] = tok;
    }
}

__global__ void init_cnt(int* cnt) { if (threadIdx.x < 8) cnt[threadIdx.x] = 0; }

__global__ void prefix_kernel(const int* __restrict__ cnt, int* __restrict__ offs) {
    if (threadIdx.x == 0) {
        int a = 0;
        for (int e = 0; e < 8; ++e) { offs[e] = a; a += cnt[e]; }
    }
}

// ---------------------------------------------------------------- Final sum
__global__ __launch_bounds__(256) void final_kernel(const float* __restrict__ x2,
                                                    const float* __restrict__ y0,
                                                    const float* __restrict__ y1,
                                                    const float* __restrict__ sh,
                                                    float* __restrict__ out) {
    size_t i = (size_t)blockIdx.x * 256 + threadIdx.x;
    float4 a = ((const float4*)x2)[i];
    float4 b = ((const float4*)y0)[i];
    float4 c = ((const float4*)y1)[i];
    float4 d = ((const float4*)sh)[i];
    float4 o;
    o.x = a.x + b.x + c.x + d.x;
    o.y = a.y + b.y + c.y + d.y;
    o.z = a.z + b.z + c.z + d.z;
    o.w = a.w + b.w + c.w + d.w;
    ((float4*)out)[i] = o;
}

#define NUL6 nullptr, nullptr, nullptr, nullptr, nullptr, nullptr

extern "C" void kernel_launch(void* const* d_in, const int* in_sizes, int n_in,
                              void* d_out, int out_size, void* d_ws, size_t ws_size,
                              hipStream_t stream) {
    const float* x   = (const float*)d_in[0];
    const int*   sp  = (const int*)d_in[1];
    const float* mask= (const float*)d_in[2];
    const float* pe  = (const float*)d_in[3];
    const float* anw = (const float*)d_in[4];
    const float* fnw = (const float*)d_in[5];
    const float* wq  = (const float*)d_in[6];  const float* bq  = (const float*)d_in[7];
    const float* wk  = (const float*)d_in[8];  const float* bk  = (const float*)d_in[9];
    const float* wv  = (const float*)d_in[10]; const float* bv  = (const float*)d_in[11];
    const float* wo  = (const float*)d_in[12]; const float* bo  = (const float*)d_in[13];
    const float* gw  = (const float*)d_in[14]; const float* gb  = (const float*)d_in[15];
    const float* ew1 = (const float*)d_in[16]; const float* eb1 = (const float*)d_in[17];
    const float* ew2 = (const float*)d_in[18]; const float* eb2 = (const float*)d_in[19];
    const float* ew3 = (const float*)d_in[20]; const float* eb3 = (const float*)d_in[21];
    const float* sw1 = (const float*)d_in[22]; const float* sb1 = (const float*)d_in[23];
    const float* sw2 = (const float*)d_in[24]; const float* sb2 = (const float*)d_in[25];
    const float* sw3 = (const float*)d_in[26]; const float* sb3 = (const float*)d_in[27];

    float* ws = (float*)d_ws;
    const size_t M2 = (size_t)2048 * 1024;
    float* xn   = ws;
    float* q    = ws + 1 * M2;
    float* kbuf = ws + 2 * M2;
    float* vbuf = ws + 3 * M2;
    float* x2   = ws + 4 * M2;
    float* amid = ws + 5 * M2;
    float* small= ws + 9 * M2;
    float* comb = small;
    int* idx0   = (int*)(small + 16384);
    int* cnt    = idx0 + 2048;
    int* offs   = cnt + 8;
    int* tok_list = offs + 8;
    float* o   = xn;
    float* hn  = q;
    float* y0  = xn;
    float* y1  = kbuf;
    float* sh  = vbuf;

    ln_kernel<<<2048, 256, 0, stream>>>(x, anw, xn);
    // QKV in one dispatch (z selects W/bias/C)
    mgemm<EPI_PLAIN, AM_DENSE, 3><<<dim3(8, 16, 3), 256, 0, stream>>>(
        xn, wq, wk, wv, bq, bk, bv, nullptr, q, kbuf, vbuf,
        2048, 1024, 1024, NUL6);
    attn_mfma<<<dim3(SS / 128, BB * HH), 256, 0, stream>>>(q, kbuf, vbuf, pe, mask, sp, o);
    mgemm<EPI_PLAIN, AM_DENSE, 1><<<dim3(8, 16), 256, 0, stream>>>(
        o, wo, nullptr, nullptr, bo, nullptr, nullptr, x, x2, nullptr, nullptr,
        2048, 1024, 1024, NUL6);
    ln_kernel<<<2048, 256, 0, stream>>>(x2, fnw, hn);
    init_cnt<<<1, 64, 0, stream>>>(cnt);
    gate_kernel<<<2048, 64, 0, stream>>>(hn, gw, gb, comb, idx0, cnt, tok_list);
    prefix_kernel<<<1, 64, 0, stream>>>(cnt, offs);
    mgemm<EPI_PLAIN, AM_GATHER, 1><<<dim3(16, 16, 8), 256, 0, stream>>>(
        hn, ew1, nullptr, nullptr, eb1, nullptr, nullptr, nullptr, amid, nullptr, nullptr,
        2048, FF, 1024, tok_list, cnt, offs, nullptr, nullptr, nullptr);
    mgemm<EPI_SILUMUL, AM_GATHER, 1><<<dim3(16, 16, 8), 256, 0, stream>>>(
        hn, ew3, nullptr, nullptr, eb3, nullptr, nullptr, amid, amid, nullptr, nullptr,
        2048, FF, 1024, tok_list, cnt, offs, nullptr, nullptr, nullptr);
    mgemm<EPI_SCATTER, AM_GROUP, 1><<<dim3(8, 16, 8), 256, 0, stream>>>(
        amid, ew2, nullptr, nullptr, eb2, nullptr, nullptr, nullptr, y0, nullptr, nullptr,
        2048, DD, FF, tok_list, cnt, offs, comb, idx0, y1);
    mgemm<EPI_PLAIN, AM_DENSE, 1><<<dim3(32, 16), 256, 0, stream>>>(
        hn, sw1, nullptr, nullptr, sb1, nullptr, nullptr, nullptr, amid, nullptr, nullptr,
        2048, FSH2, 1024, NUL6);
    mgemm<EPI_SILUMUL, AM_DENSE, 1><<<dim3(32, 16), 256, 0, stream>>>(
        hn, sw3, nullptr, nullptr, sb3, nullptr, nullptr, amid, amid, nullptr, nullptr,
        2048, FSH2, 1024, NUL6);
    mgemm<EPI_PLAIN, AM_DENSE, 1><<<dim3(8, 16), 256, 0, stream>>>(
        amid, sw2, nullptr, nullptr, sb2, nullptr, nullptr, nullptr, sh, nullptr, nullptr,
        2048, DD, FSH2, NUL6);
    final_kernel<<<2048, 256, 0, stream>>>(x2, y0, y1, sh, (float*)d_out);
}